// Round 1
// baseline (1483.926 us; speedup 1.0000x reference)
//
#include <hip/hip_runtime.h>

#define TM 32

__device__ __forceinline__ float leaky01(float v) { return v >= 0.f ? v : 0.01f * v; }

// Fused 3-layer MLP: 256 -> 128 (leaky) -> 128 (leaky) -> 256
// If flag != nullptr: only rows with flag[row]==1 are written (call with Y==X
// for the conditional in-place case; unflagged rows keep their value).
__global__ __launch_bounds__(256) void mlp3_kernel(
    const float* __restrict__ X, float* __restrict__ Y,
    const float* __restrict__ W1, const float* __restrict__ b1,
    const float* __restrict__ W2, const float* __restrict__ b2,
    const float* __restrict__ W3, const float* __restrict__ b3,
    int M, const int* __restrict__ flag)
{
    __shared__ float xs[TM * 256];   // input tile; reused as y2 (TM*128) in layer 3
    __shared__ float y1[TM * 128];
    const int tid = threadIdx.x;
    const int row0 = blockIdx.x * TM;

    // stage X tile (TM x 256) with float4 loads
    {
        const float4* src4 = (const float4*)(X + (size_t)row0 * 256);
        float4* dst4 = (float4*)xs;
#pragma unroll
        for (int i = 0; i < 8; ++i) {
            int t = i * 256 + tid;        // 0..2047, 64 float4 per row
            int rr = t >> 6;
            float4 v = make_float4(0.f, 0.f, 0.f, 0.f);
            if (row0 + rr < M) v = src4[t];
            dst4[t] = v;
        }
    }
    __syncthreads();

    const int j = tid & 127;
    const int rh = (tid >> 7) * 16;

    // ---- layer 1: 256 -> 128
    float acc[16];
#pragma unroll
    for (int i = 0; i < 16; ++i) acc[i] = 0.f;
    for (int k = 0; k < 256; k += 4) {
        float wa = W1[(k + 0) * 128 + j];
        float wb = W1[(k + 1) * 128 + j];
        float wc = W1[(k + 2) * 128 + j];
        float wd = W1[(k + 3) * 128 + j];
#pragma unroll
        for (int i = 0; i < 16; ++i) {
            float4 xv = *(const float4*)&xs[(rh + i) * 256 + k];
            acc[i] += xv.x * wa + xv.y * wb + xv.z * wc + xv.w * wd;
        }
    }
    {
        float bb = b1[j];
#pragma unroll
        for (int i = 0; i < 16; ++i)
            y1[(rh + i) * 128 + j] = leaky01(acc[i] + bb);
    }
    __syncthreads();

    // ---- layer 2: 128 -> 128  (y1 -> y2, y2 aliased onto xs)
    float* y2 = xs;
#pragma unroll
    for (int i = 0; i < 16; ++i) acc[i] = 0.f;
    for (int k = 0; k < 128; k += 4) {
        float wa = W2[(k + 0) * 128 + j];
        float wb = W2[(k + 1) * 128 + j];
        float wc = W2[(k + 2) * 128 + j];
        float wd = W2[(k + 3) * 128 + j];
#pragma unroll
        for (int i = 0; i < 16; ++i) {
            float4 xv = *(const float4*)&y1[(rh + i) * 128 + k];
            acc[i] += xv.x * wa + xv.y * wb + xv.z * wc + xv.w * wd;
        }
    }
    {
        float bb = b2[j];
#pragma unroll
        for (int i = 0; i < 16; ++i)
            y2[(rh + i) * 128 + j] = leaky01(acc[i] + bb);
    }
    __syncthreads();

    // ---- layer 3: 128 -> 256
    const int j3 = tid;
    float acc3[32];
#pragma unroll
    for (int i = 0; i < 32; ++i) acc3[i] = 0.f;
    for (int k = 0; k < 128; k += 4) {
        float wa = W3[(k + 0) * 256 + j3];
        float wb = W3[(k + 1) * 256 + j3];
        float wc = W3[(k + 2) * 256 + j3];
        float wd = W3[(k + 3) * 256 + j3];
#pragma unroll
        for (int i = 0; i < 32; ++i) {
            float4 xv = *(const float4*)&y2[i * 128 + k];
            acc3[i] += xv.x * wa + xv.y * wb + xv.z * wc + xv.w * wd;
        }
    }
    {
        float bb = b3[j3];
#pragma unroll
        for (int i = 0; i < 32; ++i) {
            int rr = row0 + i;
            if (rr < M && (flag == nullptr || flag[rr] == 1))
                Y[(size_t)rr * 256 + j3] = acc3[i] + bb;
        }
    }
}

// proj head: 256 -> 256 (relu) -> 256
__global__ __launch_bounds__(256) void proj_kernel(
    const float* __restrict__ X, float* __restrict__ Y,
    const float* __restrict__ P1, const float* __restrict__ pb1,
    const float* __restrict__ P2, const float* __restrict__ pb2,
    int M)
{
    __shared__ float xs[TM * 256];
    __shared__ float y1[TM * 256];
    const int tid = threadIdx.x;
    const int row0 = blockIdx.x * TM;

    {
        const float4* src4 = (const float4*)(X + (size_t)row0 * 256);
        float4* dst4 = (float4*)xs;
#pragma unroll
        for (int i = 0; i < 8; ++i) {
            int t = i * 256 + tid;
            int rr = t >> 6;
            float4 v = make_float4(0.f, 0.f, 0.f, 0.f);
            if (row0 + rr < M) v = src4[t];
            dst4[t] = v;
        }
    }
    __syncthreads();

    const int j = tid;
    float acc[32];
#pragma unroll
    for (int i = 0; i < 32; ++i) acc[i] = 0.f;
    for (int k = 0; k < 256; k += 4) {
        float wa = P1[(k + 0) * 256 + j];
        float wb = P1[(k + 1) * 256 + j];
        float wc = P1[(k + 2) * 256 + j];
        float wd = P1[(k + 3) * 256 + j];
#pragma unroll
        for (int i = 0; i < 32; ++i) {
            float4 xv = *(const float4*)&xs[i * 256 + k];
            acc[i] += xv.x * wa + xv.y * wb + xv.z * wc + xv.w * wd;
        }
    }
    {
        float bb = pb1[j];
#pragma unroll
        for (int i = 0; i < 32; ++i)
            y1[i * 256 + j] = fmaxf(acc[i] + bb, 0.f);
    }
    __syncthreads();

#pragma unroll
    for (int i = 0; i < 32; ++i) acc[i] = 0.f;
    for (int k = 0; k < 256; k += 4) {
        float wa = P2[(k + 0) * 256 + j];
        float wb = P2[(k + 1) * 256 + j];
        float wc = P2[(k + 2) * 256 + j];
        float wd = P2[(k + 3) * 256 + j];
#pragma unroll
        for (int i = 0; i < 32; ++i) {
            float4 xv = *(const float4*)&y1[i * 256 + k];
            acc[i] += xv.x * wa + xv.y * wb + xv.z * wc + xv.w * wd;
        }
    }
    {
        float bb = pb2[j];
#pragma unroll
        for (int i = 0; i < 32; ++i) {
            int rr = row0 + i;
            if (rr < M)
                Y[(size_t)rr * 256 + j] = acc[i] + bb;
        }
    }
}

__global__ void count_kernel(const int* __restrict__ dst, int* __restrict__ cnt, int E)
{
    int e = blockIdx.x * blockDim.x + threadIdx.x;
    if (e < E) atomicAdd(&cnt[dst[e]], 1);
}

__global__ void scan_kernel(const int* __restrict__ cnt, int* __restrict__ offs,
                            int* __restrict__ cursor, int Nn)
{
    __shared__ int sums[1024];
    int tid = threadIdx.x;
    int CH = (Nn + 1023) >> 10;
    int base = tid * CH;
    int s = 0;
    for (int i = 0; i < CH; ++i) {
        int idx = base + i;
        if (idx < Nn) s += cnt[idx];
    }
    sums[tid] = s;
    __syncthreads();
    for (int off = 1; off < 1024; off <<= 1) {
        int u = 0;
        if (tid >= off) u = sums[tid - off];
        __syncthreads();
        sums[tid] += u;
        __syncthreads();
    }
    int run = (tid > 0) ? sums[tid - 1] : 0;
    for (int i = 0; i < CH; ++i) {
        int idx = base + i;
        if (idx < Nn) {
            offs[idx] = run;
            cursor[idx] = run;
            run += cnt[idx];
        }
    }
}

__global__ void fill_kernel(const int* __restrict__ dst, int* __restrict__ cursor,
                            int* __restrict__ eidx, int E)
{
    int e = blockIdx.x * blockDim.x + threadIdx.x;
    if (e < E) {
        int p = atomicAdd(&cursor[dst[e]], 1);
        eidx[p] = e;
    }
}

// one wave (64 lanes) per destination node; lane holds 4 of the 256 features
__global__ __launch_bounds__(256) void mean_kernel(
    const float* __restrict__ h, const float* __restrict__ hinv,
    const int* __restrict__ src, const int* __restrict__ r,
    const int* __restrict__ eidx, const int* __restrict__ offs,
    const int* __restrict__ cnt, float* __restrict__ neigh, int Nn)
{
    int wid = blockIdx.x * 4 + (threadIdx.x >> 6);
    int lane = threadIdx.x & 63;
    if (wid >= Nn) return;
    int beg = offs[wid];
    int c = cnt[wid];
    int end = beg + c;
    float ax = 0.f, ay = 0.f, az = 0.f, aw = 0.f;
    for (int p = beg; p < end; ++p) {
        int e = eidx[p];
        int s = src[e];
        const float* base = (r[e] == 1 ? hinv : h) + (size_t)s * 256;
        float4 v = *(const float4*)(base + lane * 4);
        ax += v.x; ay += v.y; az += v.z; aw += v.w;
    }
    float invc = 1.0f / fmaxf((float)c, 1.0f);
    float4 o = make_float4(ax * invc, ay * invc, az * invc, aw * invc);
    *(float4*)(neigh + (size_t)wid * 256 + lane * 4) = o;
}

extern "C" void kernel_launch(void* const* d_in, const int* in_sizes, int n_in,
                              void* d_out, int out_size, void* d_ws, size_t ws_size,
                              hipStream_t stream)
{
    const float* h   = (const float*)d_in[0];
    const int* src   = (const int*)d_in[1];
    const int* dst   = (const int*)d_in[2];
    const int* r     = (const int*)d_in[3];
    const int* inv   = (const int*)d_in[4];
    const float* iW1 = (const float*)d_in[5];
    const float* ib1 = (const float*)d_in[6];
    const float* iW2 = (const float*)d_in[7];
    const float* ib2 = (const float*)d_in[8];
    const float* iW3 = (const float*)d_in[9];
    const float* ib3 = (const float*)d_in[10];
    const float* aW1 = (const float*)d_in[11];
    const float* ab1 = (const float*)d_in[12];
    const float* aW2 = (const float*)d_in[13];
    const float* ab2 = (const float*)d_in[14];
    const float* aW3 = (const float*)d_in[15];
    const float* ab3 = (const float*)d_in[16];
    const float* pW1 = (const float*)d_in[17];
    const float* pb1 = (const float*)d_in[18];
    const float* pW2 = (const float*)d_in[19];
    const float* pb2 = (const float*)d_in[20];

    const int N = in_sizes[0] / 256;
    const int E = in_sizes[1];
    float* out = (float*)d_out;

    // workspace carve-up (~106 MB)
    float* hinv  = (float*)d_ws;                     // N*256 floats (later reused as `res`)
    float* neigh = hinv + (size_t)N * 256;           // N*256 floats
    int* cnt    = (int*)(neigh + (size_t)N * 256);   // N
    int* offs   = cnt + N;                           // N
    int* cursor = offs + N;                          // N
    int* eidx   = cursor + N;                        // E

    (void)hipMemsetAsync(cnt, 0, (size_t)N * sizeof(int), stream);

    const int mlpBlocks = (N + TM - 1) / TM;

    // 1) hinv = MLP_inv(h) over nodes (edge MLP collapsed to node MLP)
    mlp3_kernel<<<mlpBlocks, 256, 0, stream>>>(h, hinv, iW1, ib1, iW2, ib2, iW3, ib3, N, nullptr);

    // 2) CSR build: count -> scan -> fill
    count_kernel<<<(E + 255) / 256, 256, 0, stream>>>(dst, cnt, E);
    scan_kernel<<<1, 1024, 0, stream>>>(cnt, offs, cursor, N);
    fill_kernel<<<(E + 255) / 256, 256, 0, stream>>>(dst, cursor, eidx, E);

    // 3) neigh = mean over incoming edges of (r ? hinv : h)[src]
    mean_kernel<<<(N + 3) / 4, 256, 0, stream>>>(h, hinv, src, r, eidx, offs, cnt, neigh, N);

    // 4) res = MLP_and(neigh); write into hinv buffer (free after mean)
    mlp3_kernel<<<mlpBlocks, 256, 0, stream>>>(neigh, hinv, aW1, ab1, aW2, ab2, aW3, ab3, N, nullptr);

    // 5) res = inv ? MLP_inv(res) : res   (in-place, conditional writes)
    mlp3_kernel<<<mlpBlocks, 256, 0, stream>>>(hinv, hinv, iW1, ib1, iW2, ib2, iW3, ib3, N, inv);

    // 6) out = relu(res @ P1 + pb1) @ P2 + pb2
    proj_kernel<<<mlpBlocks, 256, 0, stream>>>(hinv, out, pW1, pb1, pW2, pb2, N);
}

// Round 2
// 722.299 us; speedup vs baseline: 2.0544x; 2.0544x over previous
//
#include <hip/hip_runtime.h>

typedef __bf16 bf16_t;
typedef bf16_t bf16x4 __attribute__((ext_vector_type(4)));
typedef bf16_t bf16x8 __attribute__((ext_vector_type(8)));
typedef float f32x4 __attribute__((ext_vector_type(4)));

#define MFMA16(a, b, c) __builtin_amdgcn_mfma_f32_16x16x32_bf16(a, b, c, 0, 0, 0)

// ---------------------------------------------------------------------------
// Weight packing: fp32 W[K][Nc] -> split bf16 (hi, lo) in B-fragment order:
//   pack[(((k>>5)*4 + ((k>>3)&3)) * Nc + n) * 8 + (k&7)]
// so a lane's 8 B-elements (k = k0 + quad*8 + j, col n = lane&15) are one
// contiguous 16B load.
// ---------------------------------------------------------------------------
__global__ void pack_all(const float* s0, const float* s1, const float* s2,
                         const float* s3, const float* s4, const float* s5,
                         const float* s6, const float* s7, bf16_t* dst)
{
    const float* srcs[8] = {s0, s1, s2, s3, s4, s5, s6, s7};
    const int lgN[8] = {7, 7, 8, 7, 7, 8, 8, 8};
    const int sz[8]  = {32768, 16384, 32768, 32768, 16384, 32768, 65536, 65536};
    const int off[8] = {0, 65536, 98304, 163840, 229376, 262144, 327680, 458752};
    int m = blockIdx.y;
    int idx = blockIdx.x * blockDim.x + threadIdx.x;
    if (idx >= sz[m]) return;
    int lg = lgN[m];
    int Nc = 1 << lg;
    int k = idx >> lg;
    int n = idx & (Nc - 1);
    float w = srcs[m][idx];
    bf16_t hi = (bf16_t)w;
    bf16_t lo = (bf16_t)(w - (float)hi);
    int p = (((k >> 5) * 4 + ((k >> 3) & 3)) * Nc + n) * 8 + (k & 7);
    bf16_t* dh = dst + off[m];
    bf16_t* dl = dh + sz[m];
    dh[p] = hi;
    dl[p] = lo;
}

// ---------------------------------------------------------------------------
// Fused 3-layer MLP via split-bf16 MFMA: 256 ->128(leaky) ->128(leaky) ->256
// 32-row tile per block, 256 threads (4 waves). If flag!=null, only rows with
// flag[row]==1 are written (Y may alias X; blocks touch disjoint rows).
// ---------------------------------------------------------------------------
__global__ __launch_bounds__(256) void mlp3_mfma(
    const float* __restrict__ X, float* __restrict__ Y,
    const bf16_t* __restrict__ W1h, const bf16_t* __restrict__ W1l,
    const bf16_t* __restrict__ W2h, const bf16_t* __restrict__ W2l,
    const bf16_t* __restrict__ W3h, const bf16_t* __restrict__ W3l,
    const float* __restrict__ b1, const float* __restrict__ b2,
    const float* __restrict__ b3, int M, const int* __restrict__ flag)
{
    __shared__ bf16_t xh[32][264];   // input / y2 (hi), pad -> 16B-aligned rows
    __shared__ bf16_t xl[32][264];
    __shared__ bf16_t yh[32][136];   // y1 (hi)
    __shared__ bf16_t yl[32][136];

    const int tid = threadIdx.x;
    const int row0 = blockIdx.x * 32;
    const int lane = tid & 63;
    const int wv = tid >> 6;
    const int qd = lane >> 4;
    const int ln = lane & 15;

    // ---- stage X (32 x 256 fp32) -> split bf16 LDS
    {
        const float4* src4 = (const float4*)(X + (size_t)row0 * 256);
#pragma unroll
        for (int i = 0; i < 8; ++i) {
            int q = i * 256 + tid;
            int row = q >> 6;
            int kc = (q & 63) * 4;
            float4 v = make_float4(0.f, 0.f, 0.f, 0.f);
            if (row0 + row < M) v = src4[q];
            bf16_t h0 = (bf16_t)v.x; bf16_t l0 = (bf16_t)(v.x - (float)h0);
            bf16_t h1 = (bf16_t)v.y; bf16_t l1 = (bf16_t)(v.y - (float)h1);
            bf16_t h2 = (bf16_t)v.z; bf16_t l2 = (bf16_t)(v.z - (float)h2);
            bf16_t h3 = (bf16_t)v.w; bf16_t l3 = (bf16_t)(v.w - (float)h3);
            bf16x4 hv = {h0, h1, h2, h3};
            bf16x4 lv = {l0, l1, l2, l3};
            *(bf16x4*)&xh[row][kc] = hv;
            *(bf16x4*)&xl[row][kc] = lv;
        }
    }
    __syncthreads();

    const f32x4 zero4 = {0.f, 0.f, 0.f, 0.f};
    const int cb = wv * 32;   // 32-col slab per wave for 128-wide layers

    // ---- layer 1: K=256 -> Nc=128
    f32x4 acc[2][2];
    acc[0][0] = zero4; acc[0][1] = zero4; acc[1][0] = zero4; acc[1][1] = zero4;
#pragma unroll
    for (int k0 = 0; k0 < 256; k0 += 32) {
        int ka = k0 + qd * 8;
        bf16x8 ah0 = *(const bf16x8*)&xh[ln][ka];
        bf16x8 ah1 = *(const bf16x8*)&xh[16 + ln][ka];
        bf16x8 al0 = *(const bf16x8*)&xl[ln][ka];
        bf16x8 al1 = *(const bf16x8*)&xl[16 + ln][ka];
        size_t bo = ((size_t)((k0 >> 5) * 4 + qd) * 128 + cb + ln) * 8;
        bf16x8 bh0 = *(const bf16x8*)(W1h + bo);
        bf16x8 bh1 = *(const bf16x8*)(W1h + bo + 128);
        bf16x8 bl0 = *(const bf16x8*)(W1l + bo);
        bf16x8 bl1 = *(const bf16x8*)(W1l + bo + 128);
        acc[0][0] = MFMA16(ah0, bh0, acc[0][0]);
        acc[0][0] = MFMA16(al0, bh0, acc[0][0]);
        acc[0][0] = MFMA16(ah0, bl0, acc[0][0]);
        acc[0][1] = MFMA16(ah0, bh1, acc[0][1]);
        acc[0][1] = MFMA16(al0, bh1, acc[0][1]);
        acc[0][1] = MFMA16(ah0, bl1, acc[0][1]);
        acc[1][0] = MFMA16(ah1, bh0, acc[1][0]);
        acc[1][0] = MFMA16(al1, bh0, acc[1][0]);
        acc[1][0] = MFMA16(ah1, bl0, acc[1][0]);
        acc[1][1] = MFMA16(ah1, bh1, acc[1][1]);
        acc[1][1] = MFMA16(al1, bh1, acc[1][1]);
        acc[1][1] = MFMA16(ah1, bl1, acc[1][1]);
    }
#pragma unroll
    for (int ct = 0; ct < 2; ++ct) {
        int col = cb + ct * 16 + ln;
        float bb = b1[col];
#pragma unroll
        for (int rt = 0; rt < 2; ++rt) {
#pragma unroll
            for (int r = 0; r < 4; ++r) {
                float v = acc[rt][ct][r] + bb;
                v = v >= 0.f ? v : 0.01f * v;
                int row = rt * 16 + qd * 4 + r;
                bf16_t h = (bf16_t)v;
                bf16_t l = (bf16_t)(v - (float)h);
                yh[row][col] = h;
                yl[row][col] = l;
            }
        }
    }
    __syncthreads();

    // ---- layer 2: K=128 -> Nc=128 (y1 -> y2, y2 stored into xh/xl)
    acc[0][0] = zero4; acc[0][1] = zero4; acc[1][0] = zero4; acc[1][1] = zero4;
#pragma unroll
    for (int k0 = 0; k0 < 128; k0 += 32) {
        int ka = k0 + qd * 8;
        bf16x8 ah0 = *(const bf16x8*)&yh[ln][ka];
        bf16x8 ah1 = *(const bf16x8*)&yh[16 + ln][ka];
        bf16x8 al0 = *(const bf16x8*)&yl[ln][ka];
        bf16x8 al1 = *(const bf16x8*)&yl[16 + ln][ka];
        size_t bo = ((size_t)((k0 >> 5) * 4 + qd) * 128 + cb + ln) * 8;
        bf16x8 bh0 = *(const bf16x8*)(W2h + bo);
        bf16x8 bh1 = *(const bf16x8*)(W2h + bo + 128);
        bf16x8 bl0 = *(const bf16x8*)(W2l + bo);
        bf16x8 bl1 = *(const bf16x8*)(W2l + bo + 128);
        acc[0][0] = MFMA16(ah0, bh0, acc[0][0]);
        acc[0][0] = MFMA16(al0, bh0, acc[0][0]);
        acc[0][0] = MFMA16(ah0, bl0, acc[0][0]);
        acc[0][1] = MFMA16(ah0, bh1, acc[0][1]);
        acc[0][1] = MFMA16(al0, bh1, acc[0][1]);
        acc[0][1] = MFMA16(ah0, bl1, acc[0][1]);
        acc[1][0] = MFMA16(ah1, bh0, acc[1][0]);
        acc[1][0] = MFMA16(al1, bh0, acc[1][0]);
        acc[1][0] = MFMA16(ah1, bl0, acc[1][0]);
        acc[1][1] = MFMA16(ah1, bh1, acc[1][1]);
        acc[1][1] = MFMA16(al1, bh1, acc[1][1]);
        acc[1][1] = MFMA16(ah1, bl1, acc[1][1]);
    }
#pragma unroll
    for (int ct = 0; ct < 2; ++ct) {
        int col = cb + ct * 16 + ln;
        float bb = b2[col];
#pragma unroll
        for (int rt = 0; rt < 2; ++rt) {
#pragma unroll
            for (int r = 0; r < 4; ++r) {
                float v = acc[rt][ct][r] + bb;
                v = v >= 0.f ? v : 0.01f * v;
                int row = rt * 16 + qd * 4 + r;
                bf16_t h = (bf16_t)v;
                bf16_t l = (bf16_t)(v - (float)h);
                xh[row][col] = h;
                xl[row][col] = l;
            }
        }
    }
    __syncthreads();

    // ---- layer 3: K=128 -> Nc=256
    const int cb3 = wv * 64;
    f32x4 acc3[2][4];
#pragma unroll
    for (int rt = 0; rt < 2; ++rt)
#pragma unroll
        for (int ct = 0; ct < 4; ++ct) acc3[rt][ct] = zero4;
#pragma unroll
    for (int k0 = 0; k0 < 128; k0 += 32) {
        int ka = k0 + qd * 8;
        bf16x8 ah0 = *(const bf16x8*)&xh[ln][ka];
        bf16x8 ah1 = *(const bf16x8*)&xh[16 + ln][ka];
        bf16x8 al0 = *(const bf16x8*)&xl[ln][ka];
        bf16x8 al1 = *(const bf16x8*)&xl[16 + ln][ka];
#pragma unroll
        for (int ct = 0; ct < 4; ++ct) {
            size_t bo = ((size_t)((k0 >> 5) * 4 + qd) * 256 + cb3 + ct * 16 + ln) * 8;
            bf16x8 bh = *(const bf16x8*)(W3h + bo);
            bf16x8 bl = *(const bf16x8*)(W3l + bo);
            acc3[0][ct] = MFMA16(ah0, bh, acc3[0][ct]);
            acc3[0][ct] = MFMA16(al0, bh, acc3[0][ct]);
            acc3[0][ct] = MFMA16(ah0, bl, acc3[0][ct]);
            acc3[1][ct] = MFMA16(ah1, bh, acc3[1][ct]);
            acc3[1][ct] = MFMA16(al1, bh, acc3[1][ct]);
            acc3[1][ct] = MFMA16(ah1, bl, acc3[1][ct]);
        }
    }
#pragma unroll
    for (int rt = 0; rt < 2; ++rt) {
#pragma unroll
        for (int r = 0; r < 4; ++r) {
            int rr = row0 + rt * 16 + qd * 4 + r;
            bool wr = (rr < M) && (flag == nullptr || flag[rr] == 1);
            if (wr) {
#pragma unroll
                for (int ct = 0; ct < 4; ++ct) {
                    int col = cb3 + ct * 16 + ln;
                    Y[(size_t)rr * 256 + col] = acc3[rt][ct][r] + b3[col];
                }
            }
        }
    }
}

// ---------------------------------------------------------------------------
// Single GEMM layer: Y[M,256] = act(X[M,256] @ W[256,256] + b). In-place safe
// (each block stages its own 32 rows before writing them back).
// ---------------------------------------------------------------------------
__global__ __launch_bounds__(256) void gemm256_mfma(
    const float* __restrict__ X, float* __restrict__ Y,
    const bf16_t* __restrict__ Wh, const bf16_t* __restrict__ Wl,
    const float* __restrict__ b, int M, int relu)
{
    __shared__ bf16_t xh[32][264];
    __shared__ bf16_t xl[32][264];

    const int tid = threadIdx.x;
    const int row0 = blockIdx.x * 32;
    const int lane = tid & 63;
    const int wv = tid >> 6;
    const int qd = lane >> 4;
    const int ln = lane & 15;

    {
        const float4* src4 = (const float4*)(X + (size_t)row0 * 256);
#pragma unroll
        for (int i = 0; i < 8; ++i) {
            int q = i * 256 + tid;
            int row = q >> 6;
            int kc = (q & 63) * 4;
            float4 v = make_float4(0.f, 0.f, 0.f, 0.f);
            if (row0 + row < M) v = src4[q];
            bf16_t h0 = (bf16_t)v.x; bf16_t l0 = (bf16_t)(v.x - (float)h0);
            bf16_t h1 = (bf16_t)v.y; bf16_t l1 = (bf16_t)(v.y - (float)h1);
            bf16_t h2 = (bf16_t)v.z; bf16_t l2 = (bf16_t)(v.z - (float)h2);
            bf16_t h3 = (bf16_t)v.w; bf16_t l3 = (bf16_t)(v.w - (float)h3);
            bf16x4 hv = {h0, h1, h2, h3};
            bf16x4 lv = {l0, l1, l2, l3};
            *(bf16x4*)&xh[row][kc] = hv;
            *(bf16x4*)&xl[row][kc] = lv;
        }
    }
    __syncthreads();

    const f32x4 zero4 = {0.f, 0.f, 0.f, 0.f};
    const int cb = wv * 64;
    f32x4 acc[2][4];
#pragma unroll
    for (int rt = 0; rt < 2; ++rt)
#pragma unroll
        for (int ct = 0; ct < 4; ++ct) acc[rt][ct] = zero4;

#pragma unroll
    for (int k0 = 0; k0 < 256; k0 += 32) {
        int ka = k0 + qd * 8;
        bf16x8 ah0 = *(const bf16x8*)&xh[ln][ka];
        bf16x8 ah1 = *(const bf16x8*)&xh[16 + ln][ka];
        bf16x8 al0 = *(const bf16x8*)&xl[ln][ka];
        bf16x8 al1 = *(const bf16x8*)&xl[16 + ln][ka];
#pragma unroll
        for (int ct = 0; ct < 4; ++ct) {
            size_t bo = ((size_t)((k0 >> 5) * 4 + qd) * 256 + cb + ct * 16 + ln) * 8;
            bf16x8 bh = *(const bf16x8*)(Wh + bo);
            bf16x8 bl = *(const bf16x8*)(Wl + bo);
            acc[0][ct] = MFMA16(ah0, bh, acc[0][ct]);
            acc[0][ct] = MFMA16(al0, bh, acc[0][ct]);
            acc[0][ct] = MFMA16(ah0, bl, acc[0][ct]);
            acc[1][ct] = MFMA16(ah1, bh, acc[1][ct]);
            acc[1][ct] = MFMA16(al1, bh, acc[1][ct]);
            acc[1][ct] = MFMA16(ah1, bl, acc[1][ct]);
        }
    }
#pragma unroll
    for (int rt = 0; rt < 2; ++rt) {
#pragma unroll
        for (int r = 0; r < 4; ++r) {
            int rr = row0 + rt * 16 + qd * 4 + r;
            if (rr < M) {
#pragma unroll
                for (int ct = 0; ct < 4; ++ct) {
                    int col = cb + ct * 16 + ln;
                    float v = acc[rt][ct][r] + b[col];
                    if (relu) v = fmaxf(v, 0.f);
                    Y[(size_t)rr * 256 + col] = v;
                }
            }
        }
    }
}

// ---------------------------------------------------------------------------
// CSR build + mean aggregation (unchanged from round 1)
// ---------------------------------------------------------------------------
__global__ void count_kernel(const int* __restrict__ dst, int* __restrict__ cnt, int E)
{
    int e = blockIdx.x * blockDim.x + threadIdx.x;
    if (e < E) atomicAdd(&cnt[dst[e]], 1);
}

__global__ void scan_kernel(const int* __restrict__ cnt, int* __restrict__ offs,
                            int* __restrict__ cursor, int Nn)
{
    __shared__ int sums[1024];
    int tid = threadIdx.x;
    int CH = (Nn + 1023) >> 10;
    int base = tid * CH;
    int s = 0;
    for (int i = 0; i < CH; ++i) {
        int idx = base + i;
        if (idx < Nn) s += cnt[idx];
    }
    sums[tid] = s;
    __syncthreads();
    for (int off = 1; off < 1024; off <<= 1) {
        int u = 0;
        if (tid >= off) u = sums[tid - off];
        __syncthreads();
        sums[tid] += u;
        __syncthreads();
    }
    int run = (tid > 0) ? sums[tid - 1] : 0;
    for (int i = 0; i < CH; ++i) {
        int idx = base + i;
        if (idx < Nn) {
            offs[idx] = run;
            cursor[idx] = run;
            run += cnt[idx];
        }
    }
}

__global__ void fill_kernel(const int* __restrict__ dst, int* __restrict__ cursor,
                            int* __restrict__ eidx, int E)
{
    int e = blockIdx.x * blockDim.x + threadIdx.x;
    if (e < E) {
        int p = atomicAdd(&cursor[dst[e]], 1);
        eidx[p] = e;
    }
}

__global__ __launch_bounds__(256) void mean_kernel(
    const float* __restrict__ h, const float* __restrict__ hinv,
    const int* __restrict__ src, const int* __restrict__ r,
    const int* __restrict__ eidx, const int* __restrict__ offs,
    const int* __restrict__ cnt, float* __restrict__ neigh, int Nn)
{
    int wid = blockIdx.x * 4 + (threadIdx.x >> 6);
    int lane = threadIdx.x & 63;
    if (wid >= Nn) return;
    int beg = offs[wid];
    int c = cnt[wid];
    int end = beg + c;
    float ax = 0.f, ay = 0.f, az = 0.f, aw = 0.f;
    for (int p = beg; p < end; ++p) {
        int e = eidx[p];
        int s = src[e];
        const float* base = (r[e] == 1 ? hinv : h) + (size_t)s * 256;
        float4 v = *(const float4*)(base + lane * 4);
        ax += v.x; ay += v.y; az += v.z; aw += v.w;
    }
    float invc = 1.0f / fmaxf((float)c, 1.0f);
    float4 o = make_float4(ax * invc, ay * invc, az * invc, aw * invc);
    *(float4*)(neigh + (size_t)wid * 256 + lane * 4) = o;
}

extern "C" void kernel_launch(void* const* d_in, const int* in_sizes, int n_in,
                              void* d_out, int out_size, void* d_ws, size_t ws_size,
                              hipStream_t stream)
{
    const float* h   = (const float*)d_in[0];
    const int* src   = (const int*)d_in[1];
    const int* dst   = (const int*)d_in[2];
    const int* r     = (const int*)d_in[3];
    const int* inv   = (const int*)d_in[4];
    const float* iW1 = (const float*)d_in[5];
    const float* ib1 = (const float*)d_in[6];
    const float* iW2 = (const float*)d_in[7];
    const float* ib2 = (const float*)d_in[8];
    const float* iW3 = (const float*)d_in[9];
    const float* ib3 = (const float*)d_in[10];
    const float* aW1 = (const float*)d_in[11];
    const float* ab1 = (const float*)d_in[12];
    const float* aW2 = (const float*)d_in[13];
    const float* ab2 = (const float*)d_in[14];
    const float* aW3 = (const float*)d_in[15];
    const float* ab3 = (const float*)d_in[16];
    const float* pW1 = (const float*)d_in[17];
    const float* pb1 = (const float*)d_in[18];
    const float* pW2 = (const float*)d_in[19];
    const float* pb2 = (const float*)d_in[20];

    const int N = in_sizes[0] / 256;
    const int E = in_sizes[1];
    float* out = (float*)d_out;

    // workspace carve-up (~56 MB): neigh lives in d_out
    float* hinv = (float*)d_ws;                    // N*256 f32
    int* cnt    = (int*)(hinv + (size_t)N * 256);  // N
    int* offs   = cnt + N;                         // N
    int* cursor = offs + N;                        // N
    int* eidx   = cursor + N;                      // E
    bf16_t* wp  = (bf16_t*)(eidx + E);             // 589824 packed bf16

    (void)hipMemsetAsync(cnt, 0, (size_t)N * sizeof(int), stream);

    // 0) pack all 8 weight matrices into split-bf16 fragment order
    pack_all<<<dim3(256, 8), 256, 0, stream>>>(iW1, iW2, iW3, aW1, aW2, aW3, pW1, pW2, wp);

    const int mlpBlocks = (N + 31) / 32;

    // packed offsets
    bf16_t* iW1h = wp + 0,      *iW1l = wp + 32768;
    bf16_t* iW2h = wp + 65536,  *iW2l = wp + 81920;
    bf16_t* iW3h = wp + 98304,  *iW3l = wp + 131072;
    bf16_t* aW1h = wp + 163840, *aW1l = wp + 196608;
    bf16_t* aW2h = wp + 229376, *aW2l = wp + 245760;
    bf16_t* aW3h = wp + 262144, *aW3l = wp + 294912;
    bf16_t* pW1h = wp + 327680, *pW1l = wp + 393216;
    bf16_t* pW2h = wp + 458752, *pW2l = wp + 524288;

    // 1) hinv = MLP_inv(h) (edge MLP collapsed onto nodes)
    mlp3_mfma<<<mlpBlocks, 256, 0, stream>>>(h, hinv, iW1h, iW1l, iW2h, iW2l,
                                             iW3h, iW3l, ib1, ib2, ib3, N, nullptr);

    // 2) CSR build
    count_kernel<<<(E + 255) / 256, 256, 0, stream>>>(dst, cnt, E);
    scan_kernel<<<1, 1024, 0, stream>>>(cnt, offs, cursor, N);
    fill_kernel<<<(E + 255) / 256, 256, 0, stream>>>(dst, cursor, eidx, E);

    // 3) neigh (in d_out) = mean over incoming edges of (r ? hinv : h)[src]
    mean_kernel<<<(N + 3) / 4, 256, 0, stream>>>(h, hinv, src, r, eidx, offs, cnt, out, N);

    // 4) res = MLP_and(neigh) -> hinv
    mlp3_mfma<<<mlpBlocks, 256, 0, stream>>>(out, hinv, aW1h, aW1l, aW2h, aW2l,
                                             aW3h, aW3l, ab1, ab2, ab3, N, nullptr);

    // 5) res = inv ? MLP_inv(res) : res (in-place, flag-conditional)
    mlp3_mfma<<<mlpBlocks, 256, 0, stream>>>(hinv, hinv, iW1h, iW1l, iW2h, iW2l,
                                             iW3h, iW3l, ib1, ib2, ib3, N, inv);

    // 6) proj head: two in-place-safe layers through d_out
    gemm256_mfma<<<mlpBlocks, 256, 0, stream>>>(hinv, out, pW1h, pW1l, pb1, N, 1);
    gemm256_mfma<<<mlpBlocks, 256, 0, stream>>>(out, out, pW2h, pW2l, pb2, N, 0);
}

// Round 3
// 674.373 us; speedup vs baseline: 2.2005x; 1.0711x over previous
//
#include <hip/hip_runtime.h>

typedef __bf16 bf16_t;
typedef bf16_t bf16x4 __attribute__((ext_vector_type(4)));
typedef bf16_t bf16x8 __attribute__((ext_vector_type(8)));
typedef float f32x4 __attribute__((ext_vector_type(4)));

#define MFMA16(a, b, c) __builtin_amdgcn_mfma_f32_16x16x32_bf16(a, b, c, 0, 0, 0)

__device__ __forceinline__ float leaky01(float v) { return v >= 0.f ? v : 0.01f * v; }

// packed-weight offsets (bf16 elements): hi at OFF, lo at OFF+size
#define OFF_IW1 0         // 256x128
#define OFF_IW2 65536     // 128x128
#define OFF_IW3 98304     // 128x256
#define OFF_AW1 163840    // 256x128
#define OFF_AW2 229376    // 128x128
#define OFF_AW3 262144    // 128x256
#define OFF_PW1 327680    // 256x256
#define OFF_PW2 458752    // 256x256
#define OFF_M3  589824    // 128x128
#define WP_TOTAL 622592

// ---------------------------------------------------------------------------
// GEMM tile: 32 rows (2 rowblocks of 16) x (NCT*16 cols per wave), K=KD.
// A from split-bf16 LDS (row stride sa elems); B from packed global hi/lo.
// ---------------------------------------------------------------------------
template<int KD, int NCT>
__device__ __forceinline__ void gemm_tile(
    const bf16_t* __restrict__ ah, const bf16_t* __restrict__ al, int sa,
    const bf16_t* __restrict__ Bh, const bf16_t* __restrict__ Bl,
    int cb, int qd, int ln, f32x4 (&acc)[2][4])
{
#pragma unroll
    for (int rt = 0; rt < 2; ++rt)
#pragma unroll
        for (int ct = 0; ct < NCT; ++ct) acc[rt][ct] = (f32x4){0.f, 0.f, 0.f, 0.f};
#pragma unroll
    for (int k0 = 0; k0 < KD; k0 += 32) {
        int ka = k0 + qd * 8;
        bf16x8 a0h = *(const bf16x8*)&ah[ln * sa + ka];
        bf16x8 a1h = *(const bf16x8*)&ah[(16 + ln) * sa + ka];
        bf16x8 a0l = *(const bf16x8*)&al[ln * sa + ka];
        bf16x8 a1l = *(const bf16x8*)&al[(16 + ln) * sa + ka];
#pragma unroll
        for (int ct = 0; ct < NCT; ++ct) {
            size_t bo = ((size_t)((k0 >> 5) * 4 + qd) * (NCT * 64) + cb + ct * 16 + ln) * 8;
            bf16x8 bh = *(const bf16x8*)(Bh + bo);
            bf16x8 bl = *(const bf16x8*)(Bl + bo);
            acc[0][ct] = MFMA16(a0h, bh, acc[0][ct]);
            acc[0][ct] = MFMA16(a0l, bh, acc[0][ct]);
            acc[0][ct] = MFMA16(a0h, bl, acc[0][ct]);
            acc[1][ct] = MFMA16(a1h, bh, acc[1][ct]);
            acc[1][ct] = MFMA16(a1l, bh, acc[1][ct]);
            acc[1][ct] = MFMA16(a1h, bl, acc[1][ct]);
        }
    }
}

// epilogue -> split-bf16 LDS, optional activation (0 none, 1 leaky, 2 relu)
template<int NCT>
__device__ __forceinline__ void epi_split(
    f32x4 (&acc)[2][4], const float* __restrict__ bias,
    int cb, int qd, int ln, bf16_t* dh, bf16_t* dl, int stride, int act)
{
#pragma unroll
    for (int ct = 0; ct < NCT; ++ct) {
        int col = cb + ct * 16 + ln;
        float bb = bias ? bias[col] : 0.f;
#pragma unroll
        for (int rt = 0; rt < 2; ++rt)
#pragma unroll
            for (int r = 0; r < 4; ++r) {
                float v = acc[rt][ct][r] + bb;
                if (act == 1) v = leaky01(v);
                else if (act == 2) v = fmaxf(v, 0.f);
                int row = rt * 16 + qd * 4 + r;
                bf16_t h = (bf16_t)v;
                dh[row * stride + col] = h;
                dl[row * stride + col] = (bf16_t)(v - (float)h);
            }
    }
}

// ---------------------------------------------------------------------------
// kernelA: per 32 rows of h -> z = h@aW1 ; y1 = leaky(h@iW1+ib1);
// y2 = leaky(y1@iW2+ib2); zinv = y2@M3 + c3.  z,zinv interleaved in zbuf.
// ---------------------------------------------------------------------------
__global__ __launch_bounds__(256) void kernelA(
    const float* __restrict__ h, float* __restrict__ zbuf,
    const bf16_t* __restrict__ wp, const float* __restrict__ ib1,
    const float* __restrict__ ib2, const float* __restrict__ c3f, int M)
{
    __shared__ bf16_t Xh[32][264], Xl[32][264];
    __shared__ bf16_t Yh[32][136], Yl[32][136];

    const int tid = threadIdx.x;
    const int row0 = blockIdx.x * 32;
    const int lane = tid & 63;
    const int wv = tid >> 6;
    const int qd = lane >> 4;
    const int ln = lane & 15;
    const int cb = wv * 32;

    // stage h (32 x 256 fp32) -> split bf16
    {
        const float4* src4 = (const float4*)(h + (size_t)row0 * 256);
#pragma unroll
        for (int i = 0; i < 8; ++i) {
            int q = i * 256 + tid;
            int row = q >> 6;
            int kc = (q & 63) * 4;
            float4 v = make_float4(0.f, 0.f, 0.f, 0.f);
            if (row0 + row < M) v = src4[q];
            bf16_t h0 = (bf16_t)v.x; bf16_t l0 = (bf16_t)(v.x - (float)h0);
            bf16_t h1 = (bf16_t)v.y; bf16_t l1 = (bf16_t)(v.y - (float)h1);
            bf16_t h2 = (bf16_t)v.z; bf16_t l2 = (bf16_t)(v.z - (float)h2);
            bf16_t h3 = (bf16_t)v.w; bf16_t l3 = (bf16_t)(v.w - (float)h3);
            *(bf16x4*)&Xh[row][kc] = (bf16x4){h0, h1, h2, h3};
            *(bf16x4*)&Xl[row][kc] = (bf16x4){l0, l1, l2, l3};
        }
    }
    __syncthreads();

    f32x4 acc[2][4];

    // z = h @ aW1  (no bias, no act) -> zbuf even rows
    gemm_tile<256, 2>(&Xh[0][0], &Xl[0][0], 264, wp + OFF_AW1, wp + OFF_AW1 + 32768, cb, qd, ln, acc);
#pragma unroll
    for (int ct = 0; ct < 2; ++ct) {
        int col = cb + ct * 16 + ln;
#pragma unroll
        for (int rt = 0; rt < 2; ++rt)
#pragma unroll
            for (int r = 0; r < 4; ++r) {
                int row = row0 + rt * 16 + qd * 4 + r;
                if (row < M) zbuf[((size_t)row * 2) * 128 + col] = acc[rt][ct][r];
            }
    }

    // inv layer1: y1 = leaky(h@iW1 + ib1)
    gemm_tile<256, 2>(&Xh[0][0], &Xl[0][0], 264, wp + OFF_IW1, wp + OFF_IW1 + 32768, cb, qd, ln, acc);
    epi_split<2>(acc, ib1, cb, qd, ln, &Yh[0][0], &Yl[0][0], 136, 1);
    __syncthreads();

    // inv layer2: y2 = leaky(y1@iW2 + ib2) -> into X buffers (h dead)
    gemm_tile<128, 2>(&Yh[0][0], &Yl[0][0], 136, wp + OFF_IW2, wp + OFF_IW2 + 16384, cb, qd, ln, acc);
    epi_split<2>(acc, ib2, cb, qd, ln, &Xh[0][0], &Xl[0][0], 264, 1);
    __syncthreads();

    // zinv = y2 @ M3 + c3 -> zbuf odd rows
    gemm_tile<128, 2>(&Xh[0][0], &Xl[0][0], 264, wp + OFF_M3, wp + OFF_M3 + 16384, cb, qd, ln, acc);
#pragma unroll
    for (int ct = 0; ct < 2; ++ct) {
        int col = cb + ct * 16 + ln;
        float bb = c3f[col];
#pragma unroll
        for (int rt = 0; rt < 2; ++rt)
#pragma unroll
            for (int r = 0; r < 4; ++r) {
                int row = row0 + rt * 16 + qd * 4 + r;
                if (row < M) zbuf[((size_t)row * 2 + 1) * 128 + col] = acc[rt][ct][r] + bb;
            }
    }
}

// ---------------------------------------------------------------------------
// kernelB: y_act [N,128] -> u=leaky(y@aW2+ab2); res=u@aW3+ab3;
// inv-MLP on all rows, select by flag into res; out = relu(res@pW1+pb1)@pW2+pb2
// ---------------------------------------------------------------------------
__global__ __launch_bounds__(256) void kernelB(
    const float* __restrict__ yact, const int* __restrict__ invf,
    float* __restrict__ out, const bf16_t* __restrict__ wp,
    const float* __restrict__ ab2, const float* __restrict__ ab3,
    const float* __restrict__ ib1, const float* __restrict__ ib2,
    const float* __restrict__ ib3, const float* __restrict__ pb1,
    const float* __restrict__ pb2, int M)
{
    __shared__ bf16_t Ch[32][264], Cl[32][264];
    __shared__ bf16_t Ah[32][136], Al[32][136];
    __shared__ int sflag[32];

    const int tid = threadIdx.x;
    const int row0 = blockIdx.x * 32;
    const int lane = tid & 63;
    const int wv = tid >> 6;
    const int qd = lane >> 4;
    const int ln = lane & 15;
    const int cb2 = wv * 32;
    const int cb4 = wv * 64;

    // stage y_act (32 x 128) -> split bf16 in A
    {
        const float4* src4 = (const float4*)(yact + (size_t)row0 * 128);
#pragma unroll
        for (int i = 0; i < 4; ++i) {
            int q = i * 256 + tid;
            int row = q >> 5;
            int kc = (q & 31) * 4;
            float4 v = make_float4(0.f, 0.f, 0.f, 0.f);
            if (row0 + row < M) v = src4[q];
            bf16_t h0 = (bf16_t)v.x; bf16_t l0 = (bf16_t)(v.x - (float)h0);
            bf16_t h1 = (bf16_t)v.y; bf16_t l1 = (bf16_t)(v.y - (float)h1);
            bf16_t h2 = (bf16_t)v.z; bf16_t l2 = (bf16_t)(v.z - (float)h2);
            bf16_t h3 = (bf16_t)v.w; bf16_t l3 = (bf16_t)(v.w - (float)h3);
            *(bf16x4*)&Ah[row][kc] = (bf16x4){h0, h1, h2, h3};
            *(bf16x4*)&Al[row][kc] = (bf16x4){l0, l1, l2, l3};
        }
        if (tid < 32) {
            int rr = row0 + tid;
            sflag[tid] = (rr < M) ? invf[rr] : 0;
        }
    }
    __syncthreads();

    f32x4 acc[2][4];

    // L2a: u = leaky(y@aW2 + ab2) -> A (in place, sync between read and write)
    gemm_tile<128, 2>(&Ah[0][0], &Al[0][0], 136, wp + OFF_AW2, wp + OFF_AW2 + 16384, cb2, qd, ln, acc);
    __syncthreads();
    epi_split<2>(acc, ab2, cb2, qd, ln, &Ah[0][0], &Al[0][0], 136, 1);
    __syncthreads();

    // L3a: res = u@aW3 + ab3 -> C
    gemm_tile<128, 4>(&Ah[0][0], &Al[0][0], 136, wp + OFF_AW3, wp + OFF_AW3 + 32768, cb4, qd, ln, acc);
    epi_split<4>(acc, ab3, cb4, qd, ln, &Ch[0][0], &Cl[0][0], 264, 0);
    __syncthreads();

    // inv layer1: t1 = leaky(res@iW1 + ib1) -> A
    gemm_tile<256, 2>(&Ch[0][0], &Cl[0][0], 264, wp + OFF_IW1, wp + OFF_IW1 + 32768, cb2, qd, ln, acc);
    epi_split<2>(acc, ib1, cb2, qd, ln, &Ah[0][0], &Al[0][0], 136, 1);
    __syncthreads();

    // inv layer2: t2 = leaky(t1@iW2 + ib2) -> A (in place)
    gemm_tile<128, 2>(&Ah[0][0], &Al[0][0], 136, wp + OFF_IW2, wp + OFF_IW2 + 16384, cb2, qd, ln, acc);
    __syncthreads();
    epi_split<2>(acc, ib2, cb2, qd, ln, &Ah[0][0], &Al[0][0], 136, 1);
    __syncthreads();

    // inv layer3: invout = t2@iW3 + ib3 -> overwrite C rows where flag set
    gemm_tile<128, 4>(&Ah[0][0], &Al[0][0], 136, wp + OFF_IW3, wp + OFF_IW3 + 32768, cb4, qd, ln, acc);
#pragma unroll
    for (int ct = 0; ct < 4; ++ct) {
        int col = cb4 + ct * 16 + ln;
        float bb = ib3[col];
#pragma unroll
        for (int rt = 0; rt < 2; ++rt)
#pragma unroll
            for (int r = 0; r < 4; ++r) {
                int row = rt * 16 + qd * 4 + r;
                if (sflag[row] == 1) {
                    float v = acc[rt][ct][r] + bb;
                    bf16_t hh = (bf16_t)v;
                    Ch[row][col] = hh;
                    Cl[row][col] = (bf16_t)(v - (float)hh);
                }
            }
    }
    __syncthreads();

    // proj1: p1 = relu(sel@pW1 + pb1) -> C (in place)
    gemm_tile<256, 4>(&Ch[0][0], &Cl[0][0], 264, wp + OFF_PW1, wp + OFF_PW1 + 65536, cb4, qd, ln, acc);
    __syncthreads();
    epi_split<4>(acc, pb1, cb4, qd, ln, &Ch[0][0], &Cl[0][0], 264, 2);
    __syncthreads();

    // proj2 -> out
    gemm_tile<256, 4>(&Ch[0][0], &Cl[0][0], 264, wp + OFF_PW2, wp + OFF_PW2 + 65536, cb4, qd, ln, acc);
#pragma unroll
    for (int ct = 0; ct < 4; ++ct) {
        int col = cb4 + ct * 16 + ln;
        float bb = pb2[col];
#pragma unroll
        for (int rt = 0; rt < 2; ++rt)
#pragma unroll
            for (int r = 0; r < 4; ++r) {
                int row = row0 + rt * 16 + qd * 4 + r;
                if (row < M) out[(size_t)row * 256 + col] = acc[rt][ct][r] + bb;
            }
    }
}

// ---------------------------------------------------------------------------
// small prep kernels
// ---------------------------------------------------------------------------
__global__ void m3_kernel(const float* __restrict__ iW3, const float* __restrict__ aW1,
                          float* __restrict__ m3f)
{
    int idx = blockIdx.x * blockDim.x + threadIdx.x;   // 16384
    int k = idx >> 7, j = idx & 127;
    float s = 0.f;
    for (int t = 0; t < 256; ++t) s += iW3[k * 256 + t] * aW1[t * 128 + j];
    m3f[idx] = s;
}

__global__ void c3_kernel(const float* __restrict__ ib3, const float* __restrict__ aW1,
                          float* __restrict__ c3f)
{
    int j = threadIdx.x;
    float s = 0.f;
    for (int t = 0; t < 256; ++t) s += ib3[t] * aW1[t * 128 + j];
    c3f[j] = s;
}

// fp32 W[K][Nc] -> split bf16 (hi,lo) in B-fragment order
__global__ void pack_all(const float* s0, const float* s1, const float* s2,
                         const float* s3, const float* s4, const float* s5,
                         const float* s6, const float* s7, const float* s8,
                         bf16_t* dst)
{
    const float* srcs[9] = {s0, s1, s2, s3, s4, s5, s6, s7, s8};
    const int lgN[9] = {7, 7, 8, 7, 7, 8, 8, 8, 7};
    const int sz[9]  = {32768, 16384, 32768, 32768, 16384, 32768, 65536, 65536, 16384};
    const int off[9] = {OFF_IW1, OFF_IW2, OFF_IW3, OFF_AW1, OFF_AW2, OFF_AW3,
                        OFF_PW1, OFF_PW2, OFF_M3};
    int m = blockIdx.y;
    int idx = blockIdx.x * blockDim.x + threadIdx.x;
    if (idx >= sz[m]) return;
    int lg = lgN[m];
    int Nc = 1 << lg;
    int k = idx >> lg;
    int n = idx & (Nc - 1);
    float w = srcs[m][idx];
    bf16_t hi = (bf16_t)w;
    bf16_t lo = (bf16_t)(w - (float)hi);
    int p = (((k >> 5) * 4 + ((k >> 3) & 3)) * Nc + n) * 8 + (k & 7);
    bf16_t* dh = dst + off[m];
    dh[p] = hi;
    dh[sz[m] + p] = lo;
}

// ---------------------------------------------------------------------------
// CSR build + 128-wide mean (+ab1, leaky fused)
// ---------------------------------------------------------------------------
__global__ void count_kernel(const int* __restrict__ dst, int* __restrict__ cnt, int E)
{
    int e = blockIdx.x * blockDim.x + threadIdx.x;
    if (e < E) atomicAdd(&cnt[dst[e]], 1);
}

__global__ void scan_kernel(const int* __restrict__ cnt, int* __restrict__ offs,
                            int* __restrict__ cursor, int Nn)
{
    __shared__ int sums[1024];
    int tid = threadIdx.x;
    int CH = (Nn + 1023) >> 10;
    int base = tid * CH;
    int s = 0;
    for (int i = 0; i < CH; ++i) {
        int idx = base + i;
        if (idx < Nn) s += cnt[idx];
    }
    sums[tid] = s;
    __syncthreads();
    for (int off = 1; off < 1024; off <<= 1) {
        int u = 0;
        if (tid >= off) u = sums[tid - off];
        __syncthreads();
        sums[tid] += u;
        __syncthreads();
    }
    int run = (tid > 0) ? sums[tid - 1] : 0;
    for (int i = 0; i < CH; ++i) {
        int idx = base + i;
        if (idx < Nn) {
            offs[idx] = run;
            cursor[idx] = run;
            run += cnt[idx];
        }
    }
}

__global__ void fill_kernel(const int* __restrict__ dst, const int* __restrict__ src,
                            const int* __restrict__ r, int* __restrict__ cursor,
                            int* __restrict__ ridx, int E)
{
    int e = blockIdx.x * blockDim.x + threadIdx.x;
    if (e < E) {
        int p = atomicAdd(&cursor[dst[e]], 1);
        ridx[p] = src[e] * 2 + r[e];
    }
}

// one wave per node; lane holds 2 of 128 features; y = leaky(mean + ab1)
__global__ __launch_bounds__(256) void mean128(
    const float* __restrict__ zbuf, const int* __restrict__ ridx,
    const int* __restrict__ offs, const int* __restrict__ cnt,
    const float* __restrict__ ab1, float* __restrict__ y, int Nn)
{
    int wid = blockIdx.x * 4 + (threadIdx.x >> 6);
    int lane = threadIdx.x & 63;
    if (wid >= Nn) return;
    int beg = offs[wid];
    int c = cnt[wid];
    float sx = 0.f, sy = 0.f;
    for (int p = beg; p < beg + c; ++p) {
        int row = ridx[p];
        float2 v = ((const float2*)(zbuf + (size_t)row * 128))[lane];
        sx += v.x; sy += v.y;
    }
    float invc = 1.0f / fmaxf((float)c, 1.0f);
    float m0 = leaky01(sx * invc + ab1[lane * 2]);
    float m1 = leaky01(sy * invc + ab1[lane * 2 + 1]);
    ((float2*)(y + (size_t)wid * 128))[lane] = make_float2(m0, m1);
}

extern "C" void kernel_launch(void* const* d_in, const int* in_sizes, int n_in,
                              void* d_out, int out_size, void* d_ws, size_t ws_size,
                              hipStream_t stream)
{
    const float* h   = (const float*)d_in[0];
    const int* src   = (const int*)d_in[1];
    const int* dst   = (const int*)d_in[2];
    const int* r     = (const int*)d_in[3];
    const int* inv   = (const int*)d_in[4];
    const float* iW1 = (const float*)d_in[5];
    const float* ib1 = (const float*)d_in[6];
    const float* iW2 = (const float*)d_in[7];
    const float* ib2 = (const float*)d_in[8];
    const float* iW3 = (const float*)d_in[9];
    const float* ib3 = (const float*)d_in[10];
    const float* aW1 = (const float*)d_in[11];
    const float* ab1 = (const float*)d_in[12];
    const float* aW2 = (const float*)d_in[13];
    const float* ab2 = (const float*)d_in[14];
    const float* aW3 = (const float*)d_in[15];
    const float* ab3 = (const float*)d_in[16];
    const float* pW1 = (const float*)d_in[17];
    const float* pb1 = (const float*)d_in[18];
    const float* pW2 = (const float*)d_in[19];
    const float* pb2 = (const float*)d_in[20];

    const int N = in_sizes[0] / 256;
    const int E = in_sizes[1];
    float* out = (float*)d_out;

    // workspace carve-up (~82 MB)
    float* zbuf = (float*)d_ws;                        // 2N*128 f32 (z/zinv interleaved)
    float* yact = zbuf + (size_t)2 * N * 128;          // N*128 f32
    int* cnt    = (int*)(yact + (size_t)N * 128);      // N
    int* offs   = cnt + N;                             // N
    int* cursor = offs + N;                            // N
    int* ridx   = cursor + N;                          // E
    bf16_t* wp  = (bf16_t*)(ridx + E);                 // WP_TOTAL packed bf16
    float* m3f  = (float*)(wp + WP_TOTAL);             // 16384
    float* c3f  = m3f + 16384;                         // 128

    (void)hipMemsetAsync(cnt, 0, (size_t)N * sizeof(int), stream);

    // 0) folded matrices + weight packing
    m3_kernel<<<64, 256, 0, stream>>>(iW3, aW1, m3f);
    c3_kernel<<<1, 128, 0, stream>>>(ib3, aW1, c3f);
    pack_all<<<dim3(256, 9), 256, 0, stream>>>(iW1, iW2, iW3, aW1, aW2, aW3,
                                               pW1, pW2, m3f, wp);

    const int tiles = (N + 31) / 32;

    // 1) per-node z / zinv (hinv fully folded away via M3)
    kernelA<<<tiles, 256, 0, stream>>>(h, zbuf, wp, ib1, ib2, c3f, N);

    // 2) CSR build (ridx = src*2 + r)
    count_kernel<<<(E + 255) / 256, 256, 0, stream>>>(dst, cnt, E);
    scan_kernel<<<1, 1024, 0, stream>>>(cnt, offs, cursor, N);
    fill_kernel<<<(E + 255) / 256, 256, 0, stream>>>(dst, src, r, cursor, ridx, E);

    // 3) y_act = leaky(mean(z/zinv rows) + ab1)
    mean128<<<(N + 3) / 4, 256, 0, stream>>>(zbuf, ridx, offs, cnt, ab1, yact, N);

    // 4) rest of node pipeline fused: L2a,L3a, cond inv-MLP, proj1, proj2
    kernelB<<<tiles, 256, 0, stream>>>(yact, inv, out, wp, ab2, ab3,
                                       ib1, ib2, ib3, pb1, pb2, N);
}

// Round 4
// 639.505 us; speedup vs baseline: 2.3204x; 1.0545x over previous
//
#include <hip/hip_runtime.h>

typedef __bf16 bf16_t;
typedef bf16_t bf16x2 __attribute__((ext_vector_type(2)));
typedef bf16_t bf16x4 __attribute__((ext_vector_type(4)));
typedef bf16_t bf16x8 __attribute__((ext_vector_type(8)));
typedef float f32x4 __attribute__((ext_vector_type(4)));

#define MFMA16(a, b, c) __builtin_amdgcn_mfma_f32_16x16x32_bf16(a, b, c, 0, 0, 0)

__device__ __forceinline__ float leaky01(float v) { return v >= 0.f ? v : 0.01f * v; }

// packed-weight offsets (bf16 elements): hi at OFF, lo at OFF+size
#define OFF_IW1 0         // 256x128
#define OFF_IW2 65536     // 128x128
#define OFF_IW3 98304     // 128x256
#define OFF_AW1 163840    // 256x128
#define OFF_AW2 229376    // 128x128
#define OFF_AW3 262144    // 128x256
#define OFF_PW1 327680    // 256x256
#define OFF_PW2 458752    // 256x256
#define OFF_M3  589824    // 128x128
#define WP_TOTAL 622592

// ---------------------------------------------------------------------------
// GEMM tile: 32 rows x (NCT*16 cols per wave), K=KD, NC = total out cols.
// A from split-bf16 LDS (row stride sa); B from packed global hi/lo.
// ---------------------------------------------------------------------------
template<int KD, int NC, int NCT>
__device__ __forceinline__ void gemm_tile(
    const bf16_t* __restrict__ ah, const bf16_t* __restrict__ al, int sa,
    const bf16_t* __restrict__ Bh, const bf16_t* __restrict__ Bl,
    int cb, int qd, int ln, f32x4 (&acc)[2][4])
{
#pragma unroll
    for (int rt = 0; rt < 2; ++rt)
#pragma unroll
        for (int ct = 0; ct < NCT; ++ct) acc[rt][ct] = (f32x4){0.f, 0.f, 0.f, 0.f};
#pragma unroll
    for (int k0 = 0; k0 < KD; k0 += 32) {
        int ka = k0 + qd * 8;
        bf16x8 a0h = *(const bf16x8*)&ah[ln * sa + ka];
        bf16x8 a1h = *(const bf16x8*)&ah[(16 + ln) * sa + ka];
        bf16x8 a0l = *(const bf16x8*)&al[ln * sa + ka];
        bf16x8 a1l = *(const bf16x8*)&al[(16 + ln) * sa + ka];
#pragma unroll
        for (int ct = 0; ct < NCT; ++ct) {
            size_t bo = ((size_t)((k0 >> 5) * 4 + qd) * NC + cb + ct * 16 + ln) * 8;
            bf16x8 bh = *(const bf16x8*)(Bh + bo);
            bf16x8 bl = *(const bf16x8*)(Bl + bo);
            acc[0][ct] = MFMA16(a0h, bh, acc[0][ct]);
            acc[0][ct] = MFMA16(a0l, bh, acc[0][ct]);
            acc[0][ct] = MFMA16(a0h, bl, acc[0][ct]);
            acc[1][ct] = MFMA16(a1h, bh, acc[1][ct]);
            acc[1][ct] = MFMA16(a1l, bh, acc[1][ct]);
            acc[1][ct] = MFMA16(a1h, bl, acc[1][ct]);
        }
    }
}

// epilogue -> split-bf16 LDS, act: 0 none, 1 leaky, 2 relu
template<int NCT>
__device__ __forceinline__ void epi_split(
    f32x4 (&acc)[2][4], const float* __restrict__ bias,
    int cb, int qd, int ln, bf16_t* dh, bf16_t* dl, int stride, int act)
{
#pragma unroll
    for (int ct = 0; ct < NCT; ++ct) {
        int col = cb + ct * 16 + ln;
        float bb = bias ? bias[col] : 0.f;
#pragma unroll
        for (int rt = 0; rt < 2; ++rt)
#pragma unroll
            for (int r = 0; r < 4; ++r) {
                float v = acc[rt][ct][r] + bb;
                if (act == 1) v = leaky01(v);
                else if (act == 2) v = fmaxf(v, 0.f);
                int row = rt * 16 + qd * 4 + r;
                bf16_t h = (bf16_t)v;
                dh[row * stride + col] = h;
                dl[row * stride + col] = (bf16_t)(v - (float)h);
            }
    }
}

// ---------------------------------------------------------------------------
// kernelA: 512 thr / 32 rows. z = h@aW1 ; y1 = leaky(h@iW1+ib1);
// y2 = leaky(y1@iW2+ib2); zinv = y2@M3 + c3.  z,zinv interleaved in zbuf.
// ---------------------------------------------------------------------------
__global__ __launch_bounds__(512) void kernelA(
    const float* __restrict__ h, float* __restrict__ zbuf,
    const bf16_t* __restrict__ wp, const float* __restrict__ ib1,
    const float* __restrict__ ib2, const float* __restrict__ c3f, int M)
{
    __shared__ bf16_t Xh[32][264], Xl[32][264];
    __shared__ bf16_t Yh[32][136], Yl[32][136];

    const int tid = threadIdx.x;
    const int row0 = blockIdx.x * 32;
    const int lane = tid & 63;
    const int wv = tid >> 6;          // 0..7
    const int qd = lane >> 4;
    const int ln = lane & 15;
    const int cb = wv * 16;           // 16-col slab per wave (128-wide stages)

    // stage h (32 x 256 fp32) -> split bf16
    {
        const float4* src4 = (const float4*)(h + (size_t)row0 * 256);
#pragma unroll
        for (int i = 0; i < 4; ++i) {
            int q = i * 512 + tid;
            int row = q >> 6;
            int kc = (q & 63) * 4;
            float4 v = make_float4(0.f, 0.f, 0.f, 0.f);
            if (row0 + row < M) v = src4[q];
            bf16_t h0 = (bf16_t)v.x; bf16_t l0 = (bf16_t)(v.x - (float)h0);
            bf16_t h1 = (bf16_t)v.y; bf16_t l1 = (bf16_t)(v.y - (float)h1);
            bf16_t h2 = (bf16_t)v.z; bf16_t l2 = (bf16_t)(v.z - (float)h2);
            bf16_t h3 = (bf16_t)v.w; bf16_t l3 = (bf16_t)(v.w - (float)h3);
            *(bf16x4*)&Xh[row][kc] = (bf16x4){h0, h1, h2, h3};
            *(bf16x4*)&Xl[row][kc] = (bf16x4){l0, l1, l2, l3};
        }
    }
    __syncthreads();

    f32x4 acc[2][4];

    // z = h @ aW1 -> zbuf even rows
    gemm_tile<256, 128, 1>(&Xh[0][0], &Xl[0][0], 264, wp + OFF_AW1, wp + OFF_AW1 + 32768, cb, qd, ln, acc);
    {
        int col = cb + ln;
#pragma unroll
        for (int rt = 0; rt < 2; ++rt)
#pragma unroll
            for (int r = 0; r < 4; ++r) {
                int row = row0 + rt * 16 + qd * 4 + r;
                if (row < M) zbuf[((size_t)row * 2) * 128 + col] = acc[rt][0][r];
            }
    }

    // inv layer1: y1 = leaky(h@iW1 + ib1) -> Y
    gemm_tile<256, 128, 1>(&Xh[0][0], &Xl[0][0], 264, wp + OFF_IW1, wp + OFF_IW1 + 32768, cb, qd, ln, acc);
    epi_split<1>(acc, ib1, cb, qd, ln, &Yh[0][0], &Yl[0][0], 136, 1);
    __syncthreads();

    // inv layer2: y2 = leaky(y1@iW2 + ib2) -> X (h dead)
    gemm_tile<128, 128, 1>(&Yh[0][0], &Yl[0][0], 136, wp + OFF_IW2, wp + OFF_IW2 + 16384, cb, qd, ln, acc);
    epi_split<1>(acc, ib2, cb, qd, ln, &Xh[0][0], &Xl[0][0], 264, 1);
    __syncthreads();

    // zinv = y2 @ M3 + c3 -> zbuf odd rows
    gemm_tile<128, 128, 1>(&Xh[0][0], &Xl[0][0], 264, wp + OFF_M3, wp + OFF_M3 + 16384, cb, qd, ln, acc);
    {
        int col = cb + ln;
        float bb = c3f[col];
#pragma unroll
        for (int rt = 0; rt < 2; ++rt)
#pragma unroll
            for (int r = 0; r < 4; ++r) {
                int row = row0 + rt * 16 + qd * 4 + r;
                if (row < M) zbuf[((size_t)row * 2 + 1) * 128 + col] = acc[rt][0][r] + bb;
            }
    }
}

// ---------------------------------------------------------------------------
// kernelB: 512 thr / 32 rows. Phase 0 = fused mean gather (y = leaky(mean+ab1))
// then u=leaky(y@aW2+ab2); res=u@aW3+ab3; inv-MLP flag-select;
// out = relu(res@pW1+pb1)@pW2+pb2.
// ---------------------------------------------------------------------------
__global__ __launch_bounds__(512) void kernelB(
    const float* __restrict__ zbuf, const int* __restrict__ ridx,
    const int* __restrict__ offs, const int* __restrict__ cnt,
    const float* __restrict__ ab1, const int* __restrict__ invf,
    float* __restrict__ out, const bf16_t* __restrict__ wp,
    const float* __restrict__ ab2, const float* __restrict__ ab3,
    const float* __restrict__ ib1, const float* __restrict__ ib2,
    const float* __restrict__ ib3, const float* __restrict__ pb1,
    const float* __restrict__ pb2, int M)
{
    __shared__ bf16_t Ch[32][264], Cl[32][264];
    __shared__ bf16_t Ah[32][136], Al[32][136];
    __shared__ int sflag[32];

    const int tid = threadIdx.x;
    const int row0 = blockIdx.x * 32;
    const int lane = tid & 63;
    const int wv = tid >> 6;
    const int qd = lane >> 4;
    const int ln = lane & 15;
    const int cb2 = wv * 16;   // 128-wide stages
    const int cb4 = wv * 32;   // 256-wide stages

    // ---- phase 0: mean gather for this block's 32 nodes -> A (split bf16)
#pragma unroll
    for (int pass = 0; pass < 4; ++pass) {
        int nl = pass * 8 + wv;          // local node 0..31
        int row = row0 + nl;
        float sx = 0.f, sy = 0.f;
        int c = 0;
        if (row < M) {
            int beg = offs[row];
            c = cnt[row];
            for (int p = beg; p < beg + c; ++p) {
                int rr = ridx[p];
                float2 v = ((const float2*)(zbuf + (size_t)rr * 128))[lane];
                sx += v.x; sy += v.y;
            }
        }
        float invc = 1.0f / fmaxf((float)c, 1.0f);
        float m0 = leaky01(sx * invc + ab1[lane * 2]);
        float m1 = leaky01(sy * invc + ab1[lane * 2 + 1]);
        bf16_t h0 = (bf16_t)m0; bf16_t l0 = (bf16_t)(m0 - (float)h0);
        bf16_t h1 = (bf16_t)m1; bf16_t l1 = (bf16_t)(m1 - (float)h1);
        *(bf16x2*)&Ah[nl][lane * 2] = (bf16x2){h0, h1};
        *(bf16x2*)&Al[nl][lane * 2] = (bf16x2){l0, l1};
    }
    if (tid < 32) {
        int rr = row0 + tid;
        sflag[tid] = (rr < M) ? invf[rr] : 0;
    }
    __syncthreads();

    f32x4 acc[2][4];

    // L2a: u = leaky(y@aW2 + ab2) -> A (in place)
    gemm_tile<128, 128, 1>(&Ah[0][0], &Al[0][0], 136, wp + OFF_AW2, wp + OFF_AW2 + 16384, cb2, qd, ln, acc);
    __syncthreads();
    epi_split<1>(acc, ab2, cb2, qd, ln, &Ah[0][0], &Al[0][0], 136, 1);
    __syncthreads();

    // L3a: res = u@aW3 + ab3 -> C
    gemm_tile<128, 256, 2>(&Ah[0][0], &Al[0][0], 136, wp + OFF_AW3, wp + OFF_AW3 + 32768, cb4, qd, ln, acc);
    epi_split<2>(acc, ab3, cb4, qd, ln, &Ch[0][0], &Cl[0][0], 264, 0);
    __syncthreads();

    // inv layer1: t1 = leaky(res@iW1 + ib1) -> A
    gemm_tile<256, 128, 1>(&Ch[0][0], &Cl[0][0], 264, wp + OFF_IW1, wp + OFF_IW1 + 32768, cb2, qd, ln, acc);
    epi_split<1>(acc, ib1, cb2, qd, ln, &Ah[0][0], &Al[0][0], 136, 1);
    __syncthreads();

    // inv layer2: t2 = leaky(t1@iW2 + ib2) -> A (in place)
    gemm_tile<128, 128, 1>(&Ah[0][0], &Al[0][0], 136, wp + OFF_IW2, wp + OFF_IW2 + 16384, cb2, qd, ln, acc);
    __syncthreads();
    epi_split<1>(acc, ib2, cb2, qd, ln, &Ah[0][0], &Al[0][0], 136, 1);
    __syncthreads();

    // inv layer3: overwrite C rows where flag set
    gemm_tile<128, 256, 2>(&Ah[0][0], &Al[0][0], 136, wp + OFF_IW3, wp + OFF_IW3 + 32768, cb4, qd, ln, acc);
#pragma unroll
    for (int ct = 0; ct < 2; ++ct) {
        int col = cb4 + ct * 16 + ln;
        float bb = ib3[col];
#pragma unroll
        for (int rt = 0; rt < 2; ++rt)
#pragma unroll
            for (int r = 0; r < 4; ++r) {
                int row = rt * 16 + qd * 4 + r;
                if (sflag[row] == 1) {
                    float v = acc[rt][ct][r] + bb;
                    bf16_t hh = (bf16_t)v;
                    Ch[row][col] = hh;
                    Cl[row][col] = (bf16_t)(v - (float)hh);
                }
            }
    }
    __syncthreads();

    // proj1: p1 = relu(sel@pW1 + pb1) -> C (in place)
    gemm_tile<256, 256, 2>(&Ch[0][0], &Cl[0][0], 264, wp + OFF_PW1, wp + OFF_PW1 + 65536, cb4, qd, ln, acc);
    __syncthreads();
    epi_split<2>(acc, pb1, cb4, qd, ln, &Ch[0][0], &Cl[0][0], 264, 2);
    __syncthreads();

    // proj2 -> out
    gemm_tile<256, 256, 2>(&Ch[0][0], &Cl[0][0], 264, wp + OFF_PW2, wp + OFF_PW2 + 65536, cb4, qd, ln, acc);
#pragma unroll
    for (int ct = 0; ct < 2; ++ct) {
        int col = cb4 + ct * 16 + ln;
        float bb = pb2[col];
#pragma unroll
        for (int rt = 0; rt < 2; ++rt)
#pragma unroll
            for (int r = 0; r < 4; ++r) {
                int row = row0 + rt * 16 + qd * 4 + r;
                if (row < M) out[(size_t)row * 256 + col] = acc[rt][ct][r] + bb;
            }
    }
}

// ---------------------------------------------------------------------------
// small prep kernels
// ---------------------------------------------------------------------------
__global__ void m3_kernel(const float* __restrict__ iW3, const float* __restrict__ aW1,
                          float* __restrict__ m3f)
{
    int idx = blockIdx.x * blockDim.x + threadIdx.x;   // 16384
    int k = idx >> 7, j = idx & 127;
    float s = 0.f;
    for (int t = 0; t < 256; ++t) s += iW3[k * 256 + t] * aW1[t * 128 + j];
    m3f[idx] = s;
}

__global__ void c3_kernel(const float* __restrict__ ib3, const float* __restrict__ aW1,
                          float* __restrict__ c3f)
{
    int j = threadIdx.x;
    float s = 0.f;
    for (int t = 0; t < 256; ++t) s += ib3[t] * aW1[t * 128 + j];
    c3f[j] = s;
}

// fp32 W[K][Nc] -> split bf16 (hi,lo) in B-fragment order
__global__ void pack_all(const float* s0, const float* s1, const float* s2,
                         const float* s3, const float* s4, const float* s5,
                         const float* s6, const float* s7, const float* s8,
                         bf16_t* dst)
{
    const float* srcs[9] = {s0, s1, s2, s3, s4, s5, s6, s7, s8};
    const int lgN[9] = {7, 7, 8, 7, 7, 8, 8, 8, 7};
    const int sz[9]  = {32768, 16384, 32768, 32768, 16384, 32768, 65536, 65536, 16384};
    const int off[9] = {OFF_IW1, OFF_IW2, OFF_IW3, OFF_AW1, OFF_AW2, OFF_AW3,
                        OFF_PW1, OFF_PW2, OFF_M3};
    int m = blockIdx.y;
    int idx = blockIdx.x * blockDim.x + threadIdx.x;
    if (idx >= sz[m]) return;
    int lg = lgN[m];
    int Nc = 1 << lg;
    int k = idx >> lg;
    int n = idx & (Nc - 1);
    float w = srcs[m][idx];
    bf16_t hi = (bf16_t)w;
    bf16_t lo = (bf16_t)(w - (float)hi);
    int p = (((k >> 5) * 4 + ((k >> 3) & 3)) * Nc + n) * 8 + (k & 7);
    bf16_t* dh = dst + off[m];
    dh[p] = hi;
    dh[sz[m] + p] = lo;
}

// ---------------------------------------------------------------------------
// CSR build
// ---------------------------------------------------------------------------
__global__ void count_kernel(const int* __restrict__ dst, int* __restrict__ cnt, int E)
{
    int e = blockIdx.x * blockDim.x + threadIdx.x;
    if (e < E) atomicAdd(&cnt[dst[e]], 1);
}

__global__ void scan_kernel(const int* __restrict__ cnt, int* __restrict__ offs,
                            int* __restrict__ cursor, int Nn)
{
    __shared__ int sums[1024];
    int tid = threadIdx.x;
    int CH = (Nn + 1023) >> 10;
    int base = tid * CH;
    int s = 0;
    for (int i = 0; i < CH; ++i) {
        int idx = base + i;
        if (idx < Nn) s += cnt[idx];
    }
    sums[tid] = s;
    __syncthreads();
    for (int off = 1; off < 1024; off <<= 1) {
        int u = 0;
        if (tid >= off) u = sums[tid - off];
        __syncthreads();
        sums[tid] += u;
        __syncthreads();
    }
    int run = (tid > 0) ? sums[tid - 1] : 0;
    for (int i = 0; i < CH; ++i) {
        int idx = base + i;
        if (idx < Nn) {
            offs[idx] = run;
            cursor[idx] = run;
            run += cnt[idx];
        }
    }
}

__global__ void fill_kernel(const int* __restrict__ dst, const int* __restrict__ src,
                            const int* __restrict__ r, int* __restrict__ cursor,
                            int* __restrict__ ridx, int E)
{
    int e = blockIdx.x * blockDim.x + threadIdx.x;
    if (e < E) {
        int p = atomicAdd(&cursor[dst[e]], 1);
        ridx[p] = src[e] * 2 + r[e];
    }
}

extern "C" void kernel_launch(void* const* d_in, const int* in_sizes, int n_in,
                              void* d_out, int out_size, void* d_ws, size_t ws_size,
                              hipStream_t stream)
{
    const float* h   = (const float*)d_in[0];
    const int* src   = (const int*)d_in[1];
    const int* dst   = (const int*)d_in[2];
    const int* r     = (const int*)d_in[3];
    const int* inv   = (const int*)d_in[4];
    const float* iW1 = (const float*)d_in[5];
    const float* ib1 = (const float*)d_in[6];
    const float* iW2 = (const float*)d_in[7];
    const float* ib2 = (const float*)d_in[8];
    const float* iW3 = (const float*)d_in[9];
    const float* ib3 = (const float*)d_in[10];
    const float* aW1 = (const float*)d_in[11];
    const float* ab1 = (const float*)d_in[12];
    const float* aW2 = (const float*)d_in[13];
    const float* ab2 = (const float*)d_in[14];
    const float* aW3 = (const float*)d_in[15];
    const float* ab3 = (const float*)d_in[16];
    const float* pW1 = (const float*)d_in[17];
    const float* pb1 = (const float*)d_in[18];
    const float* pW2 = (const float*)d_in[19];
    const float* pb2 = (const float*)d_in[20];

    const int N = in_sizes[0] / 256;
    const int E = in_sizes[1];
    float* out = (float*)d_out;

    // workspace carve-up
    float* zbuf = (float*)d_ws;                        // 2N*128 f32 (z/zinv interleaved)
    int* cnt    = (int*)(zbuf + (size_t)2 * N * 128);  // N
    int* offs   = cnt + N;                             // N
    int* cursor = offs + N;                            // N
    int* ridx   = cursor + N;                          // E
    bf16_t* wp  = (bf16_t*)(ridx + E);                 // WP_TOTAL packed bf16
    float* m3f  = (float*)(wp + WP_TOTAL);             // 16384
    float* c3f  = m3f + 16384;                         // 128

    (void)hipMemsetAsync(cnt, 0, (size_t)N * sizeof(int), stream);

    // 0) folded matrices + weight packing
    m3_kernel<<<64, 256, 0, stream>>>(iW3, aW1, m3f);
    c3_kernel<<<1, 128, 0, stream>>>(ib3, aW1, c3f);
    pack_all<<<dim3(256, 9), 256, 0, stream>>>(iW1, iW2, iW3, aW1, aW2, aW3,
                                               pW1, pW2, m3f, wp);

    const int tiles = (N + 31) / 32;

    // 1) per-node z / zinv
    kernelA<<<tiles, 512, 0, stream>>>(h, zbuf, wp, ib1, ib2, c3f, N);

    // 2) CSR build (ridx = src*2 + r)
    count_kernel<<<(E + 255) / 256, 256, 0, stream>>>(dst, cnt, E);
    scan_kernel<<<1, 1024, 0, stream>>>(cnt, offs, cursor, N);
    fill_kernel<<<(E + 255) / 256, 256, 0, stream>>>(dst, src, r, cursor, ridx, E);

    // 3) fused: mean gather + L2a,L3a + cond inv-MLP + proj1,proj2
    kernelB<<<tiles, 512, 0, stream>>>(zbuf, ridx, offs, cnt, ab1, inv, out, wp,
                                       ab2, ab3, ib1, ib2, ib3, pb1, pb2, N);
}

// Round 5
// 452.388 us; speedup vs baseline: 3.2802x; 1.4136x over previous
//
#include <hip/hip_runtime.h>

typedef __bf16 bf16_t;
typedef _Float16 f16_t;
typedef f16_t f16x2 __attribute__((ext_vector_type(2)));
typedef bf16_t bf16x2 __attribute__((ext_vector_type(2)));
typedef bf16_t bf16x4 __attribute__((ext_vector_type(4)));
typedef bf16_t bf16x8 __attribute__((ext_vector_type(8)));
typedef float f32x4 __attribute__((ext_vector_type(4)));

#define MFMA16(a, b, c) __builtin_amdgcn_mfma_f32_16x16x32_bf16(a, b, c, 0, 0, 0)

__device__ __forceinline__ float leaky01(float v) { return v >= 0.f ? v : 0.01f * v; }

// packed-weight offsets (bf16 elements): hi at OFF, lo at OFF+size
#define OFF_IW1 0         // 256x128
#define OFF_IW2 65536     // 128x128
#define OFF_IW3 98304     // 128x256
#define OFF_AW1 163840    // 256x128
#define OFF_AW2 229376    // 128x128
#define OFF_AW3 262144    // 128x256
#define OFF_PW1 327680    // 256x256
#define OFF_PW2 458752    // 256x256
#define OFF_M3  589824    // 128x128
#define WP_TOTAL 622592

// ---------------------------------------------------------------------------
// GEMM tile: 32 rows x (NCT*16 cols per wave), K=KD, NC = total out cols.
// ---------------------------------------------------------------------------
template<int KD, int NC, int NCT>
__device__ __forceinline__ void gemm_tile(
    const bf16_t* __restrict__ ah, const bf16_t* __restrict__ al, int sa,
    const bf16_t* __restrict__ Bh, const bf16_t* __restrict__ Bl,
    int cb, int qd, int ln, f32x4 (&acc)[2][4])
{
#pragma unroll
    for (int rt = 0; rt < 2; ++rt)
#pragma unroll
        for (int ct = 0; ct < NCT; ++ct) acc[rt][ct] = (f32x4){0.f, 0.f, 0.f, 0.f};
#pragma unroll
    for (int k0 = 0; k0 < KD; k0 += 32) {
        int ka = k0 + qd * 8;
        bf16x8 a0h = *(const bf16x8*)&ah[ln * sa + ka];
        bf16x8 a1h = *(const bf16x8*)&ah[(16 + ln) * sa + ka];
        bf16x8 a0l = *(const bf16x8*)&al[ln * sa + ka];
        bf16x8 a1l = *(const bf16x8*)&al[(16 + ln) * sa + ka];
#pragma unroll
        for (int ct = 0; ct < NCT; ++ct) {
            size_t bo = ((size_t)((k0 >> 5) * 4 + qd) * NC + cb + ct * 16 + ln) * 8;
            bf16x8 bh = *(const bf16x8*)(Bh + bo);
            bf16x8 bl = *(const bf16x8*)(Bl + bo);
            acc[0][ct] = MFMA16(a0h, bh, acc[0][ct]);
            acc[0][ct] = MFMA16(a0l, bh, acc[0][ct]);
            acc[0][ct] = MFMA16(a0h, bl, acc[0][ct]);
            acc[1][ct] = MFMA16(a1h, bh, acc[1][ct]);
            acc[1][ct] = MFMA16(a1l, bh, acc[1][ct]);
            acc[1][ct] = MFMA16(a1h, bl, acc[1][ct]);
        }
    }
}

// epilogue -> split-bf16 LDS, act: 0 none, 1 leaky, 2 relu
template<int NCT>
__device__ __forceinline__ void epi_split(
    f32x4 (&acc)[2][4], const float* __restrict__ bias,
    int cb, int qd, int ln, bf16_t* dh, bf16_t* dl, int stride, int act)
{
#pragma unroll
    for (int ct = 0; ct < NCT; ++ct) {
        int col = cb + ct * 16 + ln;
        float bb = bias ? bias[col] : 0.f;
#pragma unroll
        for (int rt = 0; rt < 2; ++rt)
#pragma unroll
            for (int r = 0; r < 4; ++r) {
                float v = acc[rt][ct][r] + bb;
                if (act == 1) v = leaky01(v);
                else if (act == 2) v = fmaxf(v, 0.f);
                int row = rt * 16 + qd * 4 + r;
                bf16_t h = (bf16_t)v;
                dh[row * stride + col] = h;
                dl[row * stride + col] = (bf16_t)(v - (float)h);
            }
    }
}

// ---------------------------------------------------------------------------
// kernelA: 512 thr / 32 rows. z = h@aW1 ; y1 = leaky(h@iW1+ib1);
// y2 = leaky(y1@iW2+ib2); zinv = y2@M3 + c3.  z,zinv (fp16) interleaved.
// ---------------------------------------------------------------------------
__global__ __launch_bounds__(512) void kernelA(
    const float* __restrict__ h, f16_t* __restrict__ zbuf,
    const bf16_t* __restrict__ wp, const float* __restrict__ ib1,
    const float* __restrict__ ib2, const float* __restrict__ c3f, int M)
{
    __shared__ bf16_t Xh[32][264], Xl[32][264];
    __shared__ bf16_t Yh[32][136], Yl[32][136];

    const int tid = threadIdx.x;
    const int row0 = blockIdx.x * 32;
    const int lane = tid & 63;
    const int wv = tid >> 6;          // 0..7
    const int qd = lane >> 4;
    const int ln = lane & 15;
    const int cb = wv * 16;

    // stage h (32 x 256 fp32) -> split bf16
    {
        const float4* src4 = (const float4*)(h + (size_t)row0 * 256);
#pragma unroll
        for (int i = 0; i < 4; ++i) {
            int q = i * 512 + tid;
            int row = q >> 6;
            int kc = (q & 63) * 4;
            float4 v = make_float4(0.f, 0.f, 0.f, 0.f);
            if (row0 + row < M) v = src4[q];
            bf16_t h0 = (bf16_t)v.x; bf16_t l0 = (bf16_t)(v.x - (float)h0);
            bf16_t h1 = (bf16_t)v.y; bf16_t l1 = (bf16_t)(v.y - (float)h1);
            bf16_t h2 = (bf16_t)v.z; bf16_t l2 = (bf16_t)(v.z - (float)h2);
            bf16_t h3 = (bf16_t)v.w; bf16_t l3 = (bf16_t)(v.w - (float)h3);
            *(bf16x4*)&Xh[row][kc] = (bf16x4){h0, h1, h2, h3};
            *(bf16x4*)&Xl[row][kc] = (bf16x4){l0, l1, l2, l3};
        }
    }
    __syncthreads();

    f32x4 acc[2][4];

    // z = h @ aW1 -> zbuf even rows (fp16)
    gemm_tile<256, 128, 1>(&Xh[0][0], &Xl[0][0], 264, wp + OFF_AW1, wp + OFF_AW1 + 32768, cb, qd, ln, acc);
    {
        int col = cb + ln;
#pragma unroll
        for (int rt = 0; rt < 2; ++rt)
#pragma unroll
            for (int r = 0; r < 4; ++r) {
                int row = row0 + rt * 16 + qd * 4 + r;
                if (row < M) zbuf[((size_t)row * 2) * 128 + col] = (f16_t)acc[rt][0][r];
            }
    }

    // inv layer1: y1 = leaky(h@iW1 + ib1) -> Y
    gemm_tile<256, 128, 1>(&Xh[0][0], &Xl[0][0], 264, wp + OFF_IW1, wp + OFF_IW1 + 32768, cb, qd, ln, acc);
    epi_split<1>(acc, ib1, cb, qd, ln, &Yh[0][0], &Yl[0][0], 136, 1);
    __syncthreads();

    // inv layer2: y2 = leaky(y1@iW2 + ib2) -> X (h dead)
    gemm_tile<128, 128, 1>(&Yh[0][0], &Yl[0][0], 136, wp + OFF_IW2, wp + OFF_IW2 + 16384, cb, qd, ln, acc);
    epi_split<1>(acc, ib2, cb, qd, ln, &Xh[0][0], &Xl[0][0], 264, 1);
    __syncthreads();

    // zinv = y2 @ M3 + c3 -> zbuf odd rows (fp16)
    gemm_tile<128, 128, 1>(&Xh[0][0], &Xl[0][0], 264, wp + OFF_M3, wp + OFF_M3 + 16384, cb, qd, ln, acc);
    {
        int col = cb + ln;
        float bb = c3f[col];
#pragma unroll
        for (int rt = 0; rt < 2; ++rt)
#pragma unroll
            for (int r = 0; r < 4; ++r) {
                int row = row0 + rt * 16 + qd * 4 + r;
                if (row < M) zbuf[((size_t)row * 2 + 1) * 128 + col] = (f16_t)(acc[rt][0][r] + bb);
            }
    }
}

// ---------------------------------------------------------------------------
// kernelB: 512 thr / 32 rows. Phase 0 = fused mean gather (fp16 zbuf, 4-deep
// unroll), then the whole node-MLP chain.
// ---------------------------------------------------------------------------
__global__ __launch_bounds__(512) void kernelB(
    const f16_t* __restrict__ zbuf, const int* __restrict__ ridx,
    const int* __restrict__ offs, const int* __restrict__ cnt,
    const float* __restrict__ ab1, const int* __restrict__ invf,
    float* __restrict__ out, const bf16_t* __restrict__ wp,
    const float* __restrict__ ab2, const float* __restrict__ ab3,
    const float* __restrict__ ib1, const float* __restrict__ ib2,
    const float* __restrict__ ib3, const float* __restrict__ pb1,
    const float* __restrict__ pb2, int M)
{
    __shared__ bf16_t Ch[32][264], Cl[32][264];
    __shared__ bf16_t Ah[32][136], Al[32][136];
    __shared__ int sflag[32];

    const int tid = threadIdx.x;
    const int row0 = blockIdx.x * 32;
    const int lane = tid & 63;
    const int wv = tid >> 6;
    const int qd = lane >> 4;
    const int ln = lane & 15;
    const int cb2 = wv * 16;
    const int cb4 = wv * 32;

    const f16x2* zp = (const f16x2*)zbuf;   // row = 64 f16x2

    // ---- phase 0: mean gather (one wave per node, 4 gathers in flight)
#pragma unroll
    for (int pass = 0; pass < 4; ++pass) {
        int nl = pass * 8 + wv;
        int row = row0 + nl;
        float sx = 0.f, sy = 0.f;
        int c = 0;
        if (row < M) {
            int beg = offs[row];
            c = cnt[row];
            int end = beg + c;
            int p = beg;
            for (; p + 4 <= end; p += 4) {
                int r0 = ridx[p], r1 = ridx[p + 1], r2 = ridx[p + 2], r3 = ridx[p + 3];
                f16x2 v0 = zp[(size_t)r0 * 64 + lane];
                f16x2 v1 = zp[(size_t)r1 * 64 + lane];
                f16x2 v2 = zp[(size_t)r2 * 64 + lane];
                f16x2 v3 = zp[(size_t)r3 * 64 + lane];
                sx += (float)v0.x + (float)v1.x + (float)v2.x + (float)v3.x;
                sy += (float)v0.y + (float)v1.y + (float)v2.y + (float)v3.y;
            }
            for (; p < end; ++p) {
                int rr = ridx[p];
                f16x2 v = zp[(size_t)rr * 64 + lane];
                sx += (float)v.x;
                sy += (float)v.y;
            }
        }
        float invc = 1.0f / fmaxf((float)c, 1.0f);
        float m0 = leaky01(sx * invc + ab1[lane * 2]);
        float m1 = leaky01(sy * invc + ab1[lane * 2 + 1]);
        bf16_t h0 = (bf16_t)m0; bf16_t l0 = (bf16_t)(m0 - (float)h0);
        bf16_t h1 = (bf16_t)m1; bf16_t l1 = (bf16_t)(m1 - (float)h1);
        *(bf16x2*)&Ah[nl][lane * 2] = (bf16x2){h0, h1};
        *(bf16x2*)&Al[nl][lane * 2] = (bf16x2){l0, l1};
    }
    if (tid < 32) {
        int rr = row0 + tid;
        sflag[tid] = (rr < M) ? invf[rr] : 0;
    }
    __syncthreads();

    f32x4 acc[2][4];

    // L2a: u = leaky(y@aW2 + ab2) -> A (in place)
    gemm_tile<128, 128, 1>(&Ah[0][0], &Al[0][0], 136, wp + OFF_AW2, wp + OFF_AW2 + 16384, cb2, qd, ln, acc);
    __syncthreads();
    epi_split<1>(acc, ab2, cb2, qd, ln, &Ah[0][0], &Al[0][0], 136, 1);
    __syncthreads();

    // L3a: res = u@aW3 + ab3 -> C
    gemm_tile<128, 256, 2>(&Ah[0][0], &Al[0][0], 136, wp + OFF_AW3, wp + OFF_AW3 + 32768, cb4, qd, ln, acc);
    epi_split<2>(acc, ab3, cb4, qd, ln, &Ch[0][0], &Cl[0][0], 264, 0);
    __syncthreads();

    // inv layer1: t1 = leaky(res@iW1 + ib1) -> A
    gemm_tile<256, 128, 1>(&Ch[0][0], &Cl[0][0], 264, wp + OFF_IW1, wp + OFF_IW1 + 32768, cb2, qd, ln, acc);
    epi_split<1>(acc, ib1, cb2, qd, ln, &Ah[0][0], &Al[0][0], 136, 1);
    __syncthreads();

    // inv layer2: t2 = leaky(t1@iW2 + ib2) -> A (in place)
    gemm_tile<128, 128, 1>(&Ah[0][0], &Al[0][0], 136, wp + OFF_IW2, wp + OFF_IW2 + 16384, cb2, qd, ln, acc);
    __syncthreads();
    epi_split<1>(acc, ib2, cb2, qd, ln, &Ah[0][0], &Al[0][0], 136, 1);
    __syncthreads();

    // inv layer3: overwrite C rows where flag set
    gemm_tile<128, 256, 2>(&Ah[0][0], &Al[0][0], 136, wp + OFF_IW3, wp + OFF_IW3 + 32768, cb4, qd, ln, acc);
#pragma unroll
    for (int ct = 0; ct < 2; ++ct) {
        int col = cb4 + ct * 16 + ln;
        float bb = ib3[col];
#pragma unroll
        for (int rt = 0; rt < 2; ++rt)
#pragma unroll
            for (int r = 0; r < 4; ++r) {
                int row = rt * 16 + qd * 4 + r;
                if (sflag[row] == 1) {
                    float v = acc[rt][ct][r] + bb;
                    bf16_t hh = (bf16_t)v;
                    Ch[row][col] = hh;
                    Cl[row][col] = (bf16_t)(v - (float)hh);
                }
            }
    }
    __syncthreads();

    // proj1: p1 = relu(sel@pW1 + pb1) -> C (in place)
    gemm_tile<256, 256, 2>(&Ch[0][0], &Cl[0][0], 264, wp + OFF_PW1, wp + OFF_PW1 + 65536, cb4, qd, ln, acc);
    __syncthreads();
    epi_split<2>(acc, pb1, cb4, qd, ln, &Ch[0][0], &Cl[0][0], 264, 2);
    __syncthreads();

    // proj2 -> out
    gemm_tile<256, 256, 2>(&Ch[0][0], &Cl[0][0], 264, wp + OFF_PW2, wp + OFF_PW2 + 65536, cb4, qd, ln, acc);
#pragma unroll
    for (int ct = 0; ct < 2; ++ct) {
        int col = cb4 + ct * 16 + ln;
        float bb = pb2[col];
#pragma unroll
        for (int rt = 0; rt < 2; ++rt)
#pragma unroll
            for (int r = 0; r < 4; ++r) {
                int row = row0 + rt * 16 + qd * 4 + r;
                if (row < M) out[(size_t)row * 256 + col] = acc[rt][ct][r] + bb;
            }
    }
}

// ---------------------------------------------------------------------------
// small prep kernels
// ---------------------------------------------------------------------------
__global__ void m3_kernel(const float* __restrict__ iW3, const float* __restrict__ aW1,
                          float* __restrict__ m3f)
{
    int idx = blockIdx.x * blockDim.x + threadIdx.x;   // 16384
    int k = idx >> 7, j = idx & 127;
    float s = 0.f;
    for (int t = 0; t < 256; ++t) s += iW3[k * 256 + t] * aW1[t * 128 + j];
    m3f[idx] = s;
}

__global__ void c3_kernel(const float* __restrict__ ib3, const float* __restrict__ aW1,
                          float* __restrict__ c3f)
{
    int j = threadIdx.x;
    float s = 0.f;
    for (int t = 0; t < 256; ++t) s += ib3[t] * aW1[t * 128 + j];
    c3f[j] = s;
}

// fp32 W[K][Nc] -> split bf16 (hi,lo) in B-fragment order
__global__ void pack_all(const float* s0, const float* s1, const float* s2,
                         const float* s3, const float* s4, const float* s5,
                         const float* s6, const float* s7, const float* s8,
                         bf16_t* dst)
{
    const float* srcs[9] = {s0, s1, s2, s3, s4, s5, s6, s7, s8};
    const int lgN[9] = {7, 7, 8, 7, 7, 8, 8, 8, 7};
    const int sz[9]  = {32768, 16384, 32768, 32768, 16384, 32768, 65536, 65536, 16384};
    const int off[9] = {OFF_IW1, OFF_IW2, OFF_IW3, OFF_AW1, OFF_AW2, OFF_AW3,
                        OFF_PW1, OFF_PW2, OFF_M3};
    int m = blockIdx.y;
    int idx = blockIdx.x * blockDim.x + threadIdx.x;
    if (idx >= sz[m]) return;
    int lg = lgN[m];
    int Nc = 1 << lg;
    int k = idx >> lg;
    int n = idx & (Nc - 1);
    float w = srcs[m][idx];
    bf16_t hi = (bf16_t)w;
    bf16_t lo = (bf16_t)(w - (float)hi);
    int p = (((k >> 5) * 4 + ((k >> 3) & 3)) * Nc + n) * 8 + (k & 7);
    bf16_t* dh = dst + off[m];
    dh[p] = hi;
    dh[sz[m] + p] = lo;
}

// ---------------------------------------------------------------------------
// CSR build: count -> 3-stage multi-block scan -> fill
// ---------------------------------------------------------------------------
__global__ void count_kernel(const int* __restrict__ dst, int* __restrict__ cnt, int E)
{
    int e = blockIdx.x * blockDim.x + threadIdx.x;
    if (e < E) atomicAdd(&cnt[dst[e]], 1);
}

__global__ void scan1(const int* __restrict__ cnt, int* __restrict__ offs,
                      int* __restrict__ bsum, int Nn)
{
    __shared__ int s[256];
    int tid = threadIdx.x;
    int g = blockIdx.x * 256 + tid;
    int v = (g < Nn) ? cnt[g] : 0;
    s[tid] = v;
    __syncthreads();
    for (int off = 1; off < 256; off <<= 1) {
        int u = (tid >= off) ? s[tid - off] : 0;
        __syncthreads();
        s[tid] += u;
        __syncthreads();
    }
    if (g < Nn) offs[g] = s[tid] - v;          // block-exclusive
    if (tid == 255) bsum[blockIdx.x] = s[255];
}

__global__ void scan2(int* __restrict__ bsum, int NB)
{
    __shared__ int s[256];
    int tid = threadIdx.x;
    if (NB > 256) {                            // safety fallback (unused at N=50k)
        if (tid == 0) {
            int run = 0;
            for (int i = 0; i < NB; ++i) { int v = bsum[i]; bsum[i] = run; run += v; }
        }
        return;
    }
    int v = (tid < NB) ? bsum[tid] : 0;
    s[tid] = v;
    __syncthreads();
    for (int off = 1; off < 256; off <<= 1) {
        int u = (tid >= off) ? s[tid - off] : 0;
        __syncthreads();
        s[tid] += u;
        __syncthreads();
    }
    if (tid < NB) bsum[tid] = s[tid] - v;      // exclusive block bases
}

__global__ void scan3(int* __restrict__ offs, const int* __restrict__ bsum,
                      int* __restrict__ cursor, int Nn)
{
    int g = blockIdx.x * 256 + threadIdx.x;
    if (g < Nn) {
        int o = offs[g] + bsum[blockIdx.x];
        offs[g] = o;
        cursor[g] = o;
    }
}

__global__ void fill_kernel(const int* __restrict__ dst, const int* __restrict__ src,
                            const int* __restrict__ r, int* __restrict__ cursor,
                            int* __restrict__ ridx, int E)
{
    int e = blockIdx.x * blockDim.x + threadIdx.x;
    if (e < E) {
        int p = atomicAdd(&cursor[dst[e]], 1);
        ridx[p] = src[e] * 2 + r[e];
    }
}

extern "C" void kernel_launch(void* const* d_in, const int* in_sizes, int n_in,
                              void* d_out, int out_size, void* d_ws, size_t ws_size,
                              hipStream_t stream)
{
    const float* h   = (const float*)d_in[0];
    const int* src   = (const int*)d_in[1];
    const int* dst   = (const int*)d_in[2];
    const int* r     = (const int*)d_in[3];
    const int* inv   = (const int*)d_in[4];
    const float* iW1 = (const float*)d_in[5];
    const float* ib1 = (const float*)d_in[6];
    const float* iW2 = (const float*)d_in[7];
    const float* ib2 = (const float*)d_in[8];
    const float* iW3 = (const float*)d_in[9];
    const float* ib3 = (const float*)d_in[10];
    const float* aW1 = (const float*)d_in[11];
    const float* ab1 = (const float*)d_in[12];
    const float* aW2 = (const float*)d_in[13];
    const float* ab2 = (const float*)d_in[14];
    const float* aW3 = (const float*)d_in[15];
    const float* ab3 = (const float*)d_in[16];
    const float* pW1 = (const float*)d_in[17];
    const float* pb1 = (const float*)d_in[18];
    const float* pW2 = (const float*)d_in[19];
    const float* pb2 = (const float*)d_in[20];

    const int N = in_sizes[0] / 256;
    const int E = in_sizes[1];
    float* out = (float*)d_out;

    // workspace carve-up
    f16_t* zbuf = (f16_t*)d_ws;                        // 2N*128 fp16 (z/zinv interleaved)
    int* cnt    = (int*)(zbuf + (size_t)2 * N * 128);  // N
    int* offs   = cnt + N;                             // N
    int* cursor = offs + N;                            // N
    int* bsum   = cursor + N;                          // 256
    int* ridx   = bsum + 256;                          // E
    bf16_t* wp  = (bf16_t*)(ridx + E);                 // WP_TOTAL packed bf16
    float* m3f  = (float*)(wp + WP_TOTAL);             // 16384
    float* c3f  = m3f + 16384;                         // 128

    (void)hipMemsetAsync(cnt, 0, (size_t)N * sizeof(int), stream);

    // 0) folded matrices + weight packing
    m3_kernel<<<64, 256, 0, stream>>>(iW3, aW1, m3f);
    c3_kernel<<<1, 128, 0, stream>>>(ib3, aW1, c3f);
    pack_all<<<dim3(256, 9), 256, 0, stream>>>(iW1, iW2, iW3, aW1, aW2, aW3,
                                               pW1, pW2, m3f, wp);

    const int tiles = (N + 31) / 32;
    const int NB = (N + 255) / 256;

    // 1) per-node z / zinv (fp16)
    kernelA<<<tiles, 512, 0, stream>>>(h, zbuf, wp, ib1, ib2, c3f, N);

    // 2) CSR build (ridx = src*2 + r)
    count_kernel<<<(E + 255) / 256, 256, 0, stream>>>(dst, cnt, E);
    scan1<<<NB, 256, 0, stream>>>(cnt, offs, bsum, N);
    scan2<<<1, 256, 0, stream>>>(bsum, NB);
    scan3<<<NB, 256, 0, stream>>>(offs, bsum, cursor, N);
    fill_kernel<<<(E + 255) / 256, 256, 0, stream>>>(dst, src, r, cursor, ridx, E);

    // 3) fused: mean gather + L2a,L3a + cond inv-MLP + proj1,proj2
    kernelB<<<tiles, 512, 0, stream>>>(zbuf, ridx, offs, cnt, ab1, inv, out, wp,
                                       ab2, ab3, ib1, ib2, ib3, pb1, pb2, N);
}

// Round 6
// 405.392 us; speedup vs baseline: 3.6605x; 1.1159x over previous
//
#include <hip/hip_runtime.h>

typedef __bf16 bf16_t;
typedef _Float16 f16_t;
typedef f16_t f16x4 __attribute__((ext_vector_type(4)));
typedef bf16_t bf16x2 __attribute__((ext_vector_type(2)));
typedef bf16_t bf16x4 __attribute__((ext_vector_type(4)));
typedef bf16_t bf16x8 __attribute__((ext_vector_type(8)));
typedef float f32x4 __attribute__((ext_vector_type(4)));

#define MFMA16(a, b, c) __builtin_amdgcn_mfma_f32_16x16x32_bf16(a, b, c, 0, 0, 0)

__device__ __forceinline__ float leaky01(float v) { return v >= 0.f ? v : 0.01f * v; }

// packed-weight offsets (bf16 elements): hi at OFF, lo at OFF+size
#define OFF_IW1 0         // 256x128
#define OFF_IW2 65536     // 128x128
#define OFF_IW3 98304     // 128x256
#define OFF_AW1 163840    // 256x128
#define OFF_AW2 229376    // 128x128
#define OFF_AW3 262144    // 128x256
#define OFF_PW1 327680    // 256x256
#define OFF_PW2 458752    // 256x256
#define OFF_M3  589824    // 128x128
#define WP_TOTAL 622592

// ---------------------------------------------------------------------------
// GEMM tile: 32 rows x (NCT*16 cols per wave), K=KD, NC = total out cols.
// ---------------------------------------------------------------------------
template<int KD, int NC, int NCT>
__device__ __forceinline__ void gemm_tile(
    const bf16_t* __restrict__ ah, const bf16_t* __restrict__ al, int sa,
    const bf16_t* __restrict__ Bh, const bf16_t* __restrict__ Bl,
    int cb, int qd, int ln, f32x4 (&acc)[2][4])
{
#pragma unroll
    for (int rt = 0; rt < 2; ++rt)
#pragma unroll
        for (int ct = 0; ct < NCT; ++ct) acc[rt][ct] = (f32x4){0.f, 0.f, 0.f, 0.f};
#pragma unroll
    for (int k0 = 0; k0 < KD; k0 += 32) {
        int ka = k0 + qd * 8;
        bf16x8 a0h = *(const bf16x8*)&ah[ln * sa + ka];
        bf16x8 a1h = *(const bf16x8*)&ah[(16 + ln) * sa + ka];
        bf16x8 a0l = *(const bf16x8*)&al[ln * sa + ka];
        bf16x8 a1l = *(const bf16x8*)&al[(16 + ln) * sa + ka];
#pragma unroll
        for (int ct = 0; ct < NCT; ++ct) {
            size_t bo = ((size_t)((k0 >> 5) * 4 + qd) * NC + cb + ct * 16 + ln) * 8;
            bf16x8 bh = *(const bf16x8*)(Bh + bo);
            bf16x8 bl = *(const bf16x8*)(Bl + bo);
            acc[0][ct] = MFMA16(a0h, bh, acc[0][ct]);
            acc[0][ct] = MFMA16(a0l, bh, acc[0][ct]);
            acc[0][ct] = MFMA16(a0h, bl, acc[0][ct]);
            acc[1][ct] = MFMA16(a1h, bh, acc[1][ct]);
            acc[1][ct] = MFMA16(a1l, bh, acc[1][ct]);
            acc[1][ct] = MFMA16(a1h, bl, acc[1][ct]);
        }
    }
}

// dual GEMM sharing A-fragments: two B matrices, two accumulators (NCT=1)
template<int KD, int NC>
__device__ __forceinline__ void gemm_tile_dual(
    const bf16_t* __restrict__ ah, const bf16_t* __restrict__ al, int sa,
    const bf16_t* __restrict__ B1h, const bf16_t* __restrict__ B1l,
    const bf16_t* __restrict__ B2h, const bf16_t* __restrict__ B2l,
    int cb, int qd, int ln, f32x4 (&acc1)[2], f32x4 (&acc2)[2])
{
    acc1[0] = (f32x4){0.f, 0.f, 0.f, 0.f}; acc1[1] = acc1[0];
    acc2[0] = acc1[0]; acc2[1] = acc1[0];
#pragma unroll
    for (int k0 = 0; k0 < KD; k0 += 32) {
        int ka = k0 + qd * 8;
        bf16x8 a0h = *(const bf16x8*)&ah[ln * sa + ka];
        bf16x8 a1h = *(const bf16x8*)&ah[(16 + ln) * sa + ka];
        bf16x8 a0l = *(const bf16x8*)&al[ln * sa + ka];
        bf16x8 a1l = *(const bf16x8*)&al[(16 + ln) * sa + ka];
        size_t bo = ((size_t)((k0 >> 5) * 4 + qd) * NC + cb + ln) * 8;
        bf16x8 b1h = *(const bf16x8*)(B1h + bo);
        bf16x8 b1l = *(const bf16x8*)(B1l + bo);
        bf16x8 b2h = *(const bf16x8*)(B2h + bo);
        bf16x8 b2l = *(const bf16x8*)(B2l + bo);
        acc1[0] = MFMA16(a0h, b1h, acc1[0]);
        acc1[0] = MFMA16(a0l, b1h, acc1[0]);
        acc1[0] = MFMA16(a0h, b1l, acc1[0]);
        acc1[1] = MFMA16(a1h, b1h, acc1[1]);
        acc1[1] = MFMA16(a1l, b1h, acc1[1]);
        acc1[1] = MFMA16(a1h, b1l, acc1[1]);
        acc2[0] = MFMA16(a0h, b2h, acc2[0]);
        acc2[0] = MFMA16(a0l, b2h, acc2[0]);
        acc2[0] = MFMA16(a0h, b2l, acc2[0]);
        acc2[1] = MFMA16(a1h, b2h, acc2[1]);
        acc2[1] = MFMA16(a1l, b2h, acc2[1]);
        acc2[1] = MFMA16(a1h, b2l, acc2[1]);
    }
}

// epilogue -> split-bf16 LDS, act: 0 none, 1 leaky, 2 relu
template<int NCT>
__device__ __forceinline__ void epi_split(
    f32x4 (&acc)[2][4], const float* __restrict__ bias,
    int cb, int qd, int ln, bf16_t* dh, bf16_t* dl, int stride, int act)
{
#pragma unroll
    for (int ct = 0; ct < NCT; ++ct) {
        int col = cb + ct * 16 + ln;
        float bb = bias ? bias[col] : 0.f;
#pragma unroll
        for (int rt = 0; rt < 2; ++rt)
#pragma unroll
            for (int r = 0; r < 4; ++r) {
                float v = acc[rt][ct][r] + bb;
                if (act == 1) v = leaky01(v);
                else if (act == 2) v = fmaxf(v, 0.f);
                int row = rt * 16 + qd * 4 + r;
                bf16_t h = (bf16_t)v;
                dh[row * stride + col] = h;
                dl[row * stride + col] = (bf16_t)(v - (float)h);
            }
    }
}

// ---------------------------------------------------------------------------
// kernelA: 512 thr / 32 rows. Dual (z = h@aW1 | y1 = leaky(h@iW1+ib1));
// y2 = leaky(y1@iW2+ib2); zinv = y2@M3 + c3.  z,zinv (fp16) interleaved.
// Extra blocks (blockIdx >= tiles) do the CSR edge count.
// ---------------------------------------------------------------------------
__global__ __launch_bounds__(512) void kernelA(
    const float* __restrict__ h, f16_t* __restrict__ zbuf,
    const bf16_t* __restrict__ wp, const float* __restrict__ ib1,
    const float* __restrict__ ib2, const float* __restrict__ c3f, int M,
    int tiles, const int* __restrict__ dstE, int* __restrict__ cnt, int E)
{
    __shared__ bf16_t Xh[32][264], Xl[32][264];
    __shared__ bf16_t Yh[32][136], Yl[32][136];

    const int tid = threadIdx.x;

    if ((int)blockIdx.x >= tiles) {   // edge-count blocks
        int e = (blockIdx.x - tiles) * 512 + tid;
        if (e < E) atomicAdd(&cnt[dstE[e]], 1);
        return;
    }

    const int row0 = blockIdx.x * 32;
    const int lane = tid & 63;
    const int wv = tid >> 6;          // 0..7
    const int qd = lane >> 4;
    const int ln = lane & 15;
    const int cb = wv * 16;

    // stage h (32 x 256 fp32) -> split bf16
    {
        const float4* src4 = (const float4*)(h + (size_t)row0 * 256);
#pragma unroll
        for (int i = 0; i < 4; ++i) {
            int q = i * 512 + tid;
            int row = q >> 6;
            int kc = (q & 63) * 4;
            float4 v = make_float4(0.f, 0.f, 0.f, 0.f);
            if (row0 + row < M) v = src4[q];
            bf16_t h0 = (bf16_t)v.x; bf16_t l0 = (bf16_t)(v.x - (float)h0);
            bf16_t h1 = (bf16_t)v.y; bf16_t l1 = (bf16_t)(v.y - (float)h1);
            bf16_t h2 = (bf16_t)v.z; bf16_t l2 = (bf16_t)(v.z - (float)h2);
            bf16_t h3 = (bf16_t)v.w; bf16_t l3 = (bf16_t)(v.w - (float)h3);
            *(bf16x4*)&Xh[row][kc] = (bf16x4){h0, h1, h2, h3};
            *(bf16x4*)&Xl[row][kc] = (bf16x4){l0, l1, l2, l3};
        }
    }
    __syncthreads();

    // dual: z = h@aW1 (acc1), y1 = leaky(h@iW1 + ib1) (acc2)
    f32x4 accz[2], accy[2];
    gemm_tile_dual<256, 128>(&Xh[0][0], &Xl[0][0], 264,
                             wp + OFF_AW1, wp + OFF_AW1 + 32768,
                             wp + OFF_IW1, wp + OFF_IW1 + 32768,
                             cb, qd, ln, accz, accy);
    {
        int col = cb + ln;
        float bb = ib1[col];
#pragma unroll
        for (int rt = 0; rt < 2; ++rt)
#pragma unroll
            for (int r = 0; r < 4; ++r) {
                int lrow = rt * 16 + qd * 4 + r;
                int row = row0 + lrow;
                if (row < M) zbuf[((size_t)row * 2) * 128 + col] = (f16_t)accz[rt][r];
                float v = leaky01(accy[rt][r] + bb);
                bf16_t hh = (bf16_t)v;
                Yh[lrow][col] = hh;
                Yl[lrow][col] = (bf16_t)(v - (float)hh);
            }
    }
    __syncthreads();

    f32x4 acc[2][4];

    // y2 = leaky(y1@iW2 + ib2) -> X (h dead)
    gemm_tile<128, 128, 1>(&Yh[0][0], &Yl[0][0], 136, wp + OFF_IW2, wp + OFF_IW2 + 16384, cb, qd, ln, acc);
    epi_split<1>(acc, ib2, cb, qd, ln, &Xh[0][0], &Xl[0][0], 264, 1);
    __syncthreads();

    // zinv = y2 @ M3 + c3 -> zbuf odd rows (fp16)
    gemm_tile<128, 128, 1>(&Xh[0][0], &Xl[0][0], 264, wp + OFF_M3, wp + OFF_M3 + 16384, cb, qd, ln, acc);
    {
        int col = cb + ln;
        float bb = c3f[col];
#pragma unroll
        for (int rt = 0; rt < 2; ++rt)
#pragma unroll
            for (int r = 0; r < 4; ++r) {
                int row = row0 + rt * 16 + qd * 4 + r;
                if (row < M) zbuf[((size_t)row * 2 + 1) * 128 + col] = (f16_t)(acc[rt][0][r] + bb);
            }
    }
}

// ---------------------------------------------------------------------------
// kernelB: 512 thr / 32 rows. Phase 0 = mean gather, half-wave per node:
// edge list loaded coalesced into registers, broadcast via shfl, row loads
// issued 8-deep. Then the whole node-MLP chain.
// ---------------------------------------------------------------------------
__global__ __launch_bounds__(512) void kernelB(
    const f16_t* __restrict__ zbuf, const int* __restrict__ ridx,
    const int* __restrict__ offs, const int* __restrict__ cnt,
    const float* __restrict__ ab1, const int* __restrict__ invf,
    float* __restrict__ out, const bf16_t* __restrict__ wp,
    const float* __restrict__ ab2, const float* __restrict__ ab3,
    const float* __restrict__ ib1, const float* __restrict__ ib2,
    const float* __restrict__ ib3, const float* __restrict__ pb1,
    const float* __restrict__ pb2, int M)
{
    __shared__ bf16_t Ch[32][264], Cl[32][264];
    __shared__ bf16_t Ah[32][136], Al[32][136];
    __shared__ int sflag[32];

    const int tid = threadIdx.x;
    const int row0 = blockIdx.x * 32;
    const int lane = tid & 63;
    const int wv = tid >> 6;
    const int qd = lane >> 4;
    const int ln = lane & 15;
    const int cb2 = wv * 16;
    const int cb4 = wv * 32;

    // ---- phase 0: mean gather, half-wave (32 lanes x f16x4 = 256B row) per node
    const int hw = tid >> 5;          // half-wave 0..15
    const int hl = tid & 31;          // lane in half
    const int hbase = lane & 32;      // shfl base within wave
    const f16x4* zp4 = (const f16x4*)zbuf;   // row = 32 f16x4

#pragma unroll
    for (int pass = 0; pass < 2; ++pass) {
        int nl = pass * 16 + hw;
        int row = row0 + nl;
        float s0 = 0.f, s1 = 0.f, s2 = 0.f, s3 = 0.f;
        int c = 0;
        if (row < M) {
            int beg = offs[row];
            c = cnt[row];
            for (int base = 0; base < c; base += 32) {
                int rem = c - base; if (rem > 32) rem = 32;
                int myr = (hl < rem) ? ridx[beg + base + hl] : 0;
                int j = 0;
                for (; j + 8 <= rem; j += 8) {
                    int r0 = __shfl(myr, hbase + j + 0);
                    int r1 = __shfl(myr, hbase + j + 1);
                    int r2 = __shfl(myr, hbase + j + 2);
                    int r3 = __shfl(myr, hbase + j + 3);
                    int r4 = __shfl(myr, hbase + j + 4);
                    int r5 = __shfl(myr, hbase + j + 5);
                    int r6 = __shfl(myr, hbase + j + 6);
                    int r7 = __shfl(myr, hbase + j + 7);
                    f16x4 v0 = zp4[(size_t)r0 * 32 + hl];
                    f16x4 v1 = zp4[(size_t)r1 * 32 + hl];
                    f16x4 v2 = zp4[(size_t)r2 * 32 + hl];
                    f16x4 v3 = zp4[(size_t)r3 * 32 + hl];
                    f16x4 v4 = zp4[(size_t)r4 * 32 + hl];
                    f16x4 v5 = zp4[(size_t)r5 * 32 + hl];
                    f16x4 v6 = zp4[(size_t)r6 * 32 + hl];
                    f16x4 v7 = zp4[(size_t)r7 * 32 + hl];
                    s0 += (float)v0.x + (float)v1.x + (float)v2.x + (float)v3.x
                        + (float)v4.x + (float)v5.x + (float)v6.x + (float)v7.x;
                    s1 += (float)v0.y + (float)v1.y + (float)v2.y + (float)v3.y
                        + (float)v4.y + (float)v5.y + (float)v6.y + (float)v7.y;
                    s2 += (float)v0.z + (float)v1.z + (float)v2.z + (float)v3.z
                        + (float)v4.z + (float)v5.z + (float)v6.z + (float)v7.z;
                    s3 += (float)v0.w + (float)v1.w + (float)v2.w + (float)v3.w
                        + (float)v4.w + (float)v5.w + (float)v6.w + (float)v7.w;
                }
                for (; j < rem; ++j) {
                    int rr = __shfl(myr, hbase + j);
                    f16x4 v = zp4[(size_t)rr * 32 + hl];
                    s0 += (float)v.x; s1 += (float)v.y;
                    s2 += (float)v.z; s3 += (float)v.w;
                }
            }
        }
        float invc = 1.0f / fmaxf((float)c, 1.0f);
        float4 bv = *(const float4*)&ab1[hl * 4];
        float m0 = leaky01(s0 * invc + bv.x);
        float m1 = leaky01(s1 * invc + bv.y);
        float m2 = leaky01(s2 * invc + bv.z);
        float m3 = leaky01(s3 * invc + bv.w);
        bf16_t h0 = (bf16_t)m0; bf16_t l0 = (bf16_t)(m0 - (float)h0);
        bf16_t h1 = (bf16_t)m1; bf16_t l1 = (bf16_t)(m1 - (float)h1);
        bf16_t h2 = (bf16_t)m2; bf16_t l2 = (bf16_t)(m2 - (float)h2);
        bf16_t h3 = (bf16_t)m3; bf16_t l3 = (bf16_t)(m3 - (float)h3);
        *(bf16x4*)&Ah[nl][hl * 4] = (bf16x4){h0, h1, h2, h3};
        *(bf16x4*)&Al[nl][hl * 4] = (bf16x4){l0, l1, l2, l3};
    }
    if (tid < 32) {
        int rr = row0 + tid;
        sflag[tid] = (rr < M) ? invf[rr] : 0;
    }
    __syncthreads();

    f32x4 acc[2][4];

    // L2a: u = leaky(y@aW2 + ab2) -> A (in place)
    gemm_tile<128, 128, 1>(&Ah[0][0], &Al[0][0], 136, wp + OFF_AW2, wp + OFF_AW2 + 16384, cb2, qd, ln, acc);
    __syncthreads();
    epi_split<1>(acc, ab2, cb2, qd, ln, &Ah[0][0], &Al[0][0], 136, 1);
    __syncthreads();

    // L3a: res = u@aW3 + ab3 -> C
    gemm_tile<128, 256, 2>(&Ah[0][0], &Al[0][0], 136, wp + OFF_AW3, wp + OFF_AW3 + 32768, cb4, qd, ln, acc);
    epi_split<2>(acc, ab3, cb4, qd, ln, &Ch[0][0], &Cl[0][0], 264, 0);
    __syncthreads();

    // inv layer1: t1 = leaky(res@iW1 + ib1) -> A
    gemm_tile<256, 128, 1>(&Ch[0][0], &Cl[0][0], 264, wp + OFF_IW1, wp + OFF_IW1 + 32768, cb2, qd, ln, acc);
    epi_split<1>(acc, ib1, cb2, qd, ln, &Ah[0][0], &Al[0][0], 136, 1);
    __syncthreads();

    // inv layer2: t2 = leaky(t1@iW2 + ib2) -> A (in place)
    gemm_tile<128, 128, 1>(&Ah[0][0], &Al[0][0], 136, wp + OFF_IW2, wp + OFF_IW2 + 16384, cb2, qd, ln, acc);
    __syncthreads();
    epi_split<1>(acc, ib2, cb2, qd, ln, &Ah[0][0], &Al[0][0], 136, 1);
    __syncthreads();

    // inv layer3: overwrite C rows where flag set
    gemm_tile<128, 256, 2>(&Ah[0][0], &Al[0][0], 136, wp + OFF_IW3, wp + OFF_IW3 + 32768, cb4, qd, ln, acc);
#pragma unroll
    for (int ct = 0; ct < 2; ++ct) {
        int col = cb4 + ct * 16 + ln;
        float bb = ib3[col];
#pragma unroll
        for (int rt = 0; rt < 2; ++rt)
#pragma unroll
            for (int r = 0; r < 4; ++r) {
                int row = rt * 16 + qd * 4 + r;
                if (sflag[row] == 1) {
                    float v = acc[rt][ct][r] + bb;
                    bf16_t hh = (bf16_t)v;
                    Ch[row][col] = hh;
                    Cl[row][col] = (bf16_t)(v - (float)hh);
                }
            }
    }
    __syncthreads();

    // proj1: p1 = relu(sel@pW1 + pb1) -> C (in place)
    gemm_tile<256, 256, 2>(&Ch[0][0], &Cl[0][0], 264, wp + OFF_PW1, wp + OFF_PW1 + 65536, cb4, qd, ln, acc);
    __syncthreads();
    epi_split<2>(acc, pb1, cb4, qd, ln, &Ch[0][0], &Cl[0][0], 264, 2);
    __syncthreads();

    // proj2 -> out
    gemm_tile<256, 256, 2>(&Ch[0][0], &Cl[0][0], 264, wp + OFF_PW2, wp + OFF_PW2 + 65536, cb4, qd, ln, acc);
#pragma unroll
    for (int ct = 0; ct < 2; ++ct) {
        int col = cb4 + ct * 16 + ln;
        float bb = pb2[col];
#pragma unroll
        for (int rt = 0; rt < 2; ++rt)
#pragma unroll
            for (int r = 0; r < 4; ++r) {
                int row = row0 + rt * 16 + qd * 4 + r;
                if (row < M) out[(size_t)row * 256 + col] = acc[rt][ct][r] + bb;
            }
    }
}

// ---------------------------------------------------------------------------
// prep: blocks 0..63 compute M3 = iW3@aW1; block 64 computes c3 = ib3@aW1
// ---------------------------------------------------------------------------
__global__ void mc3_kernel(const float* __restrict__ iW3, const float* __restrict__ aW1,
                           const float* __restrict__ ib3, float* __restrict__ m3f,
                           float* __restrict__ c3f)
{
    int b = blockIdx.x;
    if (b < 64) {
        int idx = b * 256 + threadIdx.x;    // 16384
        int k = idx >> 7, j = idx & 127;
        float s = 0.f;
        for (int t = 0; t < 256; ++t) s += iW3[k * 256 + t] * aW1[t * 128 + j];
        m3f[idx] = s;
    } else {
        int j = threadIdx.x;
        if (j < 128) {
            float s = 0.f;
            for (int t = 0; t < 256; ++t) s += ib3[t] * aW1[t * 128 + j];
            c3f[j] = s;
        }
    }
}

// fp32 W[K][Nc] -> split bf16 (hi,lo) in B-fragment order
__global__ void pack_all(const float* s0, const float* s1, const float* s2,
                         const float* s3, const float* s4, const float* s5,
                         const float* s6, const float* s7, const float* s8,
                         bf16_t* dst)
{
    const float* srcs[9] = {s0, s1, s2, s3, s4, s5, s6, s7, s8};
    const int lgN[9] = {7, 7, 8, 7, 7, 8, 8, 8, 7};
    const int sz[9]  = {32768, 16384, 32768, 32768, 16384, 32768, 65536, 65536, 16384};
    const int off[9] = {OFF_IW1, OFF_IW2, OFF_IW3, OFF_AW1, OFF_AW2, OFF_AW3,
                        OFF_PW1, OFF_PW2, OFF_M3};
    int m = blockIdx.y;
    int idx = blockIdx.x * blockDim.x + threadIdx.x;
    if (idx >= sz[m]) return;
    int lg = lgN[m];
    int Nc = 1 << lg;
    int k = idx >> lg;
    int n = idx & (Nc - 1);
    float w = srcs[m][idx];
    bf16_t hi = (bf16_t)w;
    bf16_t lo = (bf16_t)(w - (float)hi);
    int p = (((k >> 5) * 4 + ((k >> 3) & 3)) * Nc + n) * 8 + (k & 7);
    bf16_t* dh = dst + off[m];
    dh[p] = hi;
    dh[sz[m] + p] = lo;
}

// ---------------------------------------------------------------------------
// CSR build: 3-stage multi-block scan -> fill (count folded into kernelA)
// ---------------------------------------------------------------------------
__global__ void scan1(const int* __restrict__ cnt, int* __restrict__ offs,
                      int* __restrict__ bsum, int Nn)
{
    __shared__ int s[256];
    int tid = threadIdx.x;
    int g = blockIdx.x * 256 + tid;
    int v = (g < Nn) ? cnt[g] : 0;
    s[tid] = v;
    __syncthreads();
    for (int off = 1; off < 256; off <<= 1) {
        int u = (tid >= off) ? s[tid - off] : 0;
        __syncthreads();
        s[tid] += u;
        __syncthreads();
    }
    if (g < Nn) offs[g] = s[tid] - v;          // block-exclusive
    if (tid == 255) bsum[blockIdx.x] = s[255];
}

__global__ void scan2(int* __restrict__ bsum, int NB)
{
    __shared__ int s[256];
    int tid = threadIdx.x;
    if (NB > 256) {                            // safety fallback (unused at N=50k)
        if (tid == 0) {
            int run = 0;
            for (int i = 0; i < NB; ++i) { int v = bsum[i]; bsum[i] = run; run += v; }
        }
        return;
    }
    int v = (tid < NB) ? bsum[tid] : 0;
    s[tid] = v;
    __syncthreads();
    for (int off = 1; off < 256; off <<= 1) {
        int u = (tid >= off) ? s[tid - off] : 0;
        __syncthreads();
        s[tid] += u;
        __syncthreads();
    }
    if (tid < NB) bsum[tid] = s[tid] - v;      // exclusive block bases
}

__global__ void scan3(int* __restrict__ offs, const int* __restrict__ bsum,
                      int* __restrict__ cursor, int Nn)
{
    int g = blockIdx.x * 256 + threadIdx.x;
    if (g < Nn) {
        int o = offs[g] + bsum[blockIdx.x];
        offs[g] = o;
        cursor[g] = o;
    }
}

__global__ void fill_kernel(const int* __restrict__ dst, const int* __restrict__ src,
                            const int* __restrict__ r, int* __restrict__ cursor,
                            int* __restrict__ ridx, int E)
{
    int e = blockIdx.x * blockDim.x + threadIdx.x;
    if (e < E) {
        int p = atomicAdd(&cursor[dst[e]], 1);
        ridx[p] = src[e] * 2 + r[e];
    }
}

extern "C" void kernel_launch(void* const* d_in, const int* in_sizes, int n_in,
                              void* d_out, int out_size, void* d_ws, size_t ws_size,
                              hipStream_t stream)
{
    const float* h   = (const float*)d_in[0];
    const int* src   = (const int*)d_in[1];
    const int* dst   = (const int*)d_in[2];
    const int* r     = (const int*)d_in[3];
    const int* inv   = (const int*)d_in[4];
    const float* iW1 = (const float*)d_in[5];
    const float* ib1 = (const float*)d_in[6];
    const float* iW2 = (const float*)d_in[7];
    const float* ib2 = (const float*)d_in[8];
    const float* iW3 = (const float*)d_in[9];
    const float* ib3 = (const float*)d_in[10];
    const float* aW1 = (const float*)d_in[11];
    const float* ab1 = (const float*)d_in[12];
    const float* aW2 = (const float*)d_in[13];
    const float* ab2 = (const float*)d_in[14];
    const float* aW3 = (const float*)d_in[15];
    const float* ab3 = (const float*)d_in[16];
    const float* pW1 = (const float*)d_in[17];
    const float* pb1 = (const float*)d_in[18];
    const float* pW2 = (const float*)d_in[19];
    const float* pb2 = (const float*)d_in[20];

    const int N = in_sizes[0] / 256;
    const int E = in_sizes[1];
    float* out = (float*)d_out;

    // workspace carve-up
    f16_t* zbuf = (f16_t*)d_ws;                        // 2N*128 fp16 (z/zinv interleaved)
    int* cnt    = (int*)(zbuf + (size_t)2 * N * 128);  // N
    int* offs   = cnt + N;                             // N
    int* cursor = offs + N;                            // N
    int* bsum   = cursor + N;                          // 256
    int* ridx   = bsum + 256;                          // E
    bf16_t* wp  = (bf16_t*)(ridx + E);                 // WP_TOTAL packed bf16
    float* m3f  = (float*)(wp + WP_TOTAL);             // 16384
    float* c3f  = m3f + 16384;                         // 128

    (void)hipMemsetAsync(cnt, 0, (size_t)N * sizeof(int), stream);

    // 0) folded matrices + weight packing
    mc3_kernel<<<65, 256, 0, stream>>>(iW3, aW1, ib3, m3f, c3f);
    pack_all<<<dim3(256, 9), 256, 0, stream>>>(iW1, iW2, iW3, aW1, aW2, aW3,
                                               pW1, pW2, m3f, wp);

    const int tiles = (N + 31) / 32;
    const int EB = (E + 511) / 512;
    const int NB = (N + 255) / 256;

    // 1) per-node z / zinv (fp16) + fused CSR edge count
    kernelA<<<tiles + EB, 512, 0, stream>>>(h, zbuf, wp, ib1, ib2, c3f, N,
                                            tiles, dst, cnt, E);

    // 2) CSR scan + fill (ridx = src*2 + r)
    scan1<<<NB, 256, 0, stream>>>(cnt, offs, bsum, N);
    scan2<<<1, 256, 0, stream>>>(bsum, NB);
    scan3<<<NB, 256, 0, stream>>>(offs, bsum, cursor, N);
    fill_kernel<<<(E + 255) / 256, 256, 0, stream>>>(dst, src, r, cursor, ridx, E);

    // 3) fused: mean gather + L2a,L3a + cond inv-MLP + proj1,proj2
    kernelB<<<tiles, 512, 0, stream>>>(zbuf, ridx, offs, cnt, ab1, inv, out, wp,
                                       ab2, ab3, ib1, ib2, ib3, pb1, pb2, N);
}